// Round 2
// baseline (1848.619 us; speedup 1.0000x reference)
//
#include <hip/hip_runtime.h>
#include <hip/hip_bf16.h>
#include <math.h>

// Shapes: B=4, C=192, H=W=128, window 16 -> 256 windows of 256 tokens, 6 heads x 32
#define HWC 16384   // 128*128
#define CCH 192

__device__ __forceinline__ float gelu_exact(float v){
  return 0.5f * v * (1.0f + erff(v * 0.70710678118654752440f));
}

// ---------------- pointwise 1x1 conv (NCHW), register-tiled GEMM -------------
// MODE 0: in = xres (x), out = gelu(conv)
// MODE 1: in = inA, out = conv
// MODE 2: in = inA*inB, out = conv + residual xres
template<int MODE>
__global__ __launch_bounds__(256) void pw_kernel(
    const float* __restrict__ xres,
    const float* __restrict__ inA,
    const float* __restrict__ inB,
    const float* __restrict__ w,     // [co][ci]
    const float* __restrict__ bias,  // [co]
    float* __restrict__ out)
{
  __shared__ float xs[96*68];
  __shared__ float wt[96*68];
  const int tid = threadIdx.x;
  const int pix0 = blockIdx.x * 64;
  const int bb = pix0 >> 14;
  const int hw0 = pix0 & (HWC-1);
  const long base = (long)bb * CCH * HWC + hw0;
  const int tp = tid & 15, tc = tid >> 4;

  float acc[3][4][4];
  #pragma unroll
  for (int coc=0; coc<3; coc++){
    #pragma unroll
    for (int u=0; u<4; u++){
      float bv = bias[coc*64 + tc*4 + u];
      #pragma unroll
      for (int v=0; v<4; v++) acc[coc][u][v] = bv;
    }
  }
  #pragma unroll
  for (int cic=0; cic<2; cic++){
    #pragma unroll
    for (int coc=0; coc<3; coc++){
      __syncthreads();
      if (coc == 0){
        #pragma unroll
        for (int i=0;i<24;i++){
          int idx = tid + i*256;
          int cil = idx >> 6, pix = idx & 63;
          long g = base + (long)(cic*96 + cil)*HWC + pix;
          float v;
          if (MODE==0)      v = xres[g];
          else if (MODE==1) v = inA[g];
          else              v = inA[g]*inB[g];
          xs[cil*68 + pix] = v;
        }
      }
      #pragma unroll
      for (int i=0;i<24;i++){
        int idx = tid + i*256;
        int cc2 = idx / 96, cil = idx - cc2*96;
        wt[cil*68 + cc2] = w[(coc*64+cc2)*CCH + cic*96 + cil];
      }
      __syncthreads();
      #pragma unroll 2
      for (int cil=0; cil<96; cil++){
        float4 xv = *(const float4*)&xs[cil*68 + tp*4];
        float4 wv = *(const float4*)&wt[cil*68 + tc*4];
        float xa[4] = {xv.x, xv.y, xv.z, xv.w};
        float wa[4] = {wv.x, wv.y, wv.z, wv.w};
        #pragma unroll
        for (int u=0;u<4;u++)
          #pragma unroll
          for (int v=0;v<4;v++)
            acc[coc][u][v] = fmaf(wa[u], xa[v], acc[coc][u][v]);
      }
    }
  }
  #pragma unroll
  for (int coc=0; coc<3; coc++){
    #pragma unroll
    for (int u=0; u<4; u++){
      int co = coc*64 + tc*4 + u;
      long g = base + (long)co*HWC + tp*4;
      float t0 = acc[coc][u][0], t1 = acc[coc][u][1];
      float t2 = acc[coc][u][2], t3 = acc[coc][u][3];
      if (MODE==0){ t0=gelu_exact(t0); t1=gelu_exact(t1); t2=gelu_exact(t2); t3=gelu_exact(t3); }
      if (MODE==2){
        float4 rv = *(const float4*)&xres[g];
        t0 += rv.x; t1 += rv.y; t2 += rv.z; t3 += rv.w;
      }
      float4 r; r.x=t0; r.y=t1; r.z=t2; r.w=t3;
      *(float4*)&out[g] = r;
    }
  }
}

// ---------------- depthwise 5x5 conv (generic pad/dil), NCHW f32 ------------
__global__ __launch_bounds__(256) void dw_kernel(
    const float* __restrict__ in, const float* __restrict__ w,
    const float* __restrict__ bias, float* __restrict__ out,
    int pad, int dil)
{
  int idx = blockIdx.x*256 + threadIdx.x;
  int wx = idx & 127;
  int hy = (idx >> 7) & 127;
  int bc = idx >> 14;            // b*192 + c
  int c  = bc % 192;
  const float* ib = in + (long)bc * HWC;
  float acc = bias[c];
  #pragma unroll
  for (int kh=0; kh<5; kh++){
    int ih = hy + kh*dil - pad;
    if ((unsigned)ih < 128u){
      const float* irow = ib + ih*128;
      #pragma unroll
      for (int kw=0; kw<5; kw++){
        int iw = wx + kw*dil - pad;
        if ((unsigned)iw < 128u)
          acc = fmaf(w[c*25 + kh*5 + kw], irow[iw], acc);
      }
    }
  }
  out[idx] = acc;
}

// ---------------- LayerNorm over C, NCHW f32 -> NHWC f32 (z) ----------------
__global__ __launch_bounds__(256) void ln_kernel(
    const float* __restrict__ in, const float* __restrict__ gam,
    const float* __restrict__ bet, float* __restrict__ z)
{
  __shared__ float xs[CCH*68];
  __shared__ float ps[4*64], ps2[4*64], smu[64], srs[64];
  const int tid = threadIdx.x;
  const int pix0 = blockIdx.x * 64;
  const int bb = pix0 >> 14;
  const int hw0 = pix0 & (HWC-1);
  const long base = (long)bb * CCH * HWC + hw0;
  #pragma unroll 8
  for (int i=0;i<48;i++){
    int idx = tid + i*256;
    int ci = idx >> 6, pix = idx & 63;
    xs[ci*68 + pix] = in[base + (long)ci*HWC + pix];
  }
  __syncthreads();
  {
    int pix = tid & 63, g = tid >> 6;
    float s=0.f, s2=0.f;
    for (int ci=g*48; ci<g*48+48; ci++){
      float v = xs[ci*68 + pix]; s += v; s2 = fmaf(v, v, s2);
    }
    ps[g*64+pix] = s; ps2[g*64+pix] = s2;
  }
  __syncthreads();
  if (tid < 64){
    float s  = ps[tid]  + ps[64+tid]  + ps[128+tid]  + ps[192+tid];
    float s2 = ps2[tid] + ps2[64+tid] + ps2[128+tid] + ps2[192+tid];
    float mu = s * (1.0f/192.0f);
    float var = s2 * (1.0f/192.0f) - mu*mu;
    smu[tid] = mu;
    srs[tid] = rsqrtf(var + 1e-5f);
  }
  __syncthreads();
  #pragma unroll 8
  for (int i=0;i<48;i++){
    int idx = tid + i*256;
    int pix = idx / 192, ci = idx - pix*192;
    float v = (xs[ci*68 + pix] - smu[pix]) * srs[pix] * gam[ci] + bet[ci];
    z[(long)(pix0 + pix)*CCH + ci] = v;
  }
}

// ---------------- qkv GEMM: z[65536][192] @ W^T[192][576] + b ---------------
__global__ __launch_bounds__(256) void qkv_kernel(
    const float* __restrict__ z,
    const float* __restrict__ w,    // [576][192]
    const float* __restrict__ qb,
    const float* __restrict__ vb,
    float* __restrict__ qkv)        // [65536][576]
{
  __shared__ float xs[96*68];
  __shared__ float wt[96*68];
  const int tid = threadIdx.x;
  const int p0 = blockIdx.x * 64;
  const int s  = blockIdx.y;       // 0=q,1=k,2=v
  const int oc_base = s*192;
  const int tp = tid & 15, tc = tid >> 4;
  #pragma unroll
  for (int coc=0; coc<3; coc++){
    float acc[4][4];
    #pragma unroll
    for (int u=0; u<4; u++){
      int ocl = coc*64 + tc*4 + u;
      float bv = (s==0) ? qb[ocl] : ((s==2) ? vb[ocl] : 0.0f);
      #pragma unroll
      for (int v=0; v<4; v++) acc[u][v] = bv;
    }
    #pragma unroll
    for (int cic=0; cic<2; cic++){
      __syncthreads();
      #pragma unroll
      for (int i=0;i<24;i++){
        int idx = tid + i*256;
        int r = idx / 96, cil = idx - r*96;
        xs[cil*68 + r] = z[(long)(p0+r)*CCH + cic*96 + cil];
      }
      #pragma unroll
      for (int i=0;i<24;i++){
        int idx = tid + i*256;
        int cc2 = idx / 96, cil = idx - cc2*96;
        wt[cil*68 + cc2] = w[(oc_base + coc*64 + cc2)*CCH + cic*96 + cil];
      }
      __syncthreads();
      #pragma unroll 2
      for (int cil=0; cil<96; cil++){
        float4 xv = *(const float4*)&xs[cil*68 + tp*4];
        float4 wv = *(const float4*)&wt[cil*68 + tc*4];
        float xa[4] = {xv.x, xv.y, xv.z, xv.w};
        float wa[4] = {wv.x, wv.y, wv.z, wv.w};
        #pragma unroll
        for (int u=0;u<4;u++)
          #pragma unroll
          for (int v=0;v<4;v++)
            acc[u][v] = fmaf(wa[u], xa[v], acc[u][v]);
      }
    }
    // transpose epilogue through LDS -> coalesced row-major stores
    __syncthreads();
    #pragma unroll
    for (int u=0;u<4;u++)
      #pragma unroll
      for (int v=0;v<4;v++)
        wt[(tp*4+v)*68 + tc*4+u] = acc[u][v];
    __syncthreads();
    #pragma unroll
    for (int i=0;i<16;i++){
      int idx = tid + i*256;
      int pl = idx >> 6, ocl = idx & 63;
      qkv[(long)(p0+pl)*576 + oc_base + coc*64 + ocl] = wt[pl*68 + ocl];
    }
  }
}

// ---------------- CPB MLP: table(961,2) -> (961,6) --------------------------
__device__ __forceinline__ float cpb_coord(int a){
  float r = ((float)a - 15.0f) * (8.0f/15.0f);
  float t = log2f(fabsf(r) + 1.0f) * (1.0f/3.0f);
  return (r < 0.f) ? -t : t;
}
__global__ __launch_bounds__(128) void cpb_mlp_kernel(
    const float* __restrict__ w1, const float* __restrict__ b1,
    const float* __restrict__ w2, float* __restrict__ tbl6)
{
  int e = blockIdx.x;
  int a = e / 31, bb = e - a*31;
  float t0 = cpb_coord(a), t1 = cpb_coord(bb);
  float p[6] = {0,0,0,0,0,0};
  for (int hh = threadIdx.x; hh < 512; hh += 128){
    float hid = t0*w1[hh*2] + t1*w1[hh*2+1] + b1[hh];
    hid = fmaxf(hid, 0.0f);
    #pragma unroll
    for (int hd=0; hd<6; hd++) p[hd] = fmaf(hid, w2[hd*512 + hh], p[hd]);
  }
  __shared__ float red[6][128];
  #pragma unroll
  for (int hd=0; hd<6; hd++) red[hd][threadIdx.x] = p[hd];
  __syncthreads();
  if (threadIdx.x < 6){
    float sum = 0.f;
    for (int i=0;i<128;i++) sum += red[threadIdx.x][i];
    tbl6[e*6 + threadIdx.x] = sum;
  }
}
// expand to bias[h][i][j] = 16*sigmoid(tbl6[relidx(i,j)][h])
__global__ __launch_bounds__(256) void cpb_expand_kernel(
    const float* __restrict__ tbl6, float* __restrict__ bias)
{
  int idx = blockIdx.x*256 + threadIdx.x;      // < 6*256*256
  int h = idx >> 16;
  int rem = idx & 65535;
  int i = rem >> 8, j = rem & 255;
  int dy = (i>>4) - (j>>4) + 15;
  int dx = (i&15) - (j&15) + 15;
  float v = tbl6[(dy*31+dx)*6 + h];
  bias[idx] = 16.0f / (1.0f + __expf(-v));
}

// ---------------- windowed cosine attention, one block per (win, head) ------
__global__ __launch_bounds__(256) void attn_kernel(
    const float* __restrict__ qkv, const float* __restrict__ bias,
    const float* __restrict__ ls, float* __restrict__ out)
{
  __shared__ float sK[256*32];   // 32 KB, unpadded: main-loop reads are broadcasts
  __shared__ float sV[256*32];   // 32 KB
  const int win = blockIdx.x, h = blockIdx.y;
  const int t = threadIdx.x;
  const int bb = win >> 6;
  const int wy = (win >> 3) & 7, wx = win & 7;
  const int ty = t >> 4, tx = t & 15;
  const int pix = bb*HWC + (wy*16+ty)*128 + wx*16 + tx;
  const float* row = qkv + (long)pix*576 + h*32;
  float q[32];
  float sq = 0.f, sk = 0.f;
  #pragma unroll
  for (int d=0; d<32; d+=4){
    float4 qv = *(const float4*)(row + d);
    float4 kv = *(const float4*)(row + 192 + d);
    float4 vv = *(const float4*)(row + 384 + d);
    q[d]=qv.x; q[d+1]=qv.y; q[d+2]=qv.z; q[d+3]=qv.w;
    sq += qv.x*qv.x + qv.y*qv.y + qv.z*qv.z + qv.w*qv.w;
    sk += kv.x*kv.x + kv.y*kv.y + kv.z*kv.z + kv.w*kv.w;
    *(float4*)&sK[t*32+d] = kv;
    *(float4*)&sV[t*32+d] = vv;
  }
  float sc = __expf(fminf(ls[h], 4.60517018598809136804f));  // ln(100)
  float qinv = sc / fmaxf(sqrtf(sq), 1e-12f);
  float kinv = 1.0f / fmaxf(sqrtf(sk), 1e-12f);
  #pragma unroll
  for (int d=0; d<32; d++) q[d] *= qinv;
  #pragma unroll
  for (int d=0; d<32; d+=4){
    float4 kv = *(float4*)&sK[t*32+d];
    kv.x*=kinv; kv.y*=kinv; kv.z*=kinv; kv.w*=kinv;
    *(float4*)&sK[t*32+d] = kv;
  }
  __syncthreads();
  const float* brow = bias + (((h<<8) + t) << 8);   // h*65536 + t*256
  float m = -1e30f, l = 0.f;
  float o[32];
  #pragma unroll
  for (int d=0; d<32; d++) o[d] = 0.f;
  for (int j=0; j<256; j++){
    const float* kr = &sK[j*32];
    float s = 0.f;
    #pragma unroll
    for (int d=0; d<32; d+=4){
      float4 kv = *(const float4*)(kr+d);
      s += q[d]*kv.x + q[d+1]*kv.y + q[d+2]*kv.z + q[d+3]*kv.w;
    }
    s += brow[j];
    float mn = fmaxf(m, s);
    float ec = __expf(m - mn);
    float e  = __expf(s - mn);
    l = l*ec + e;
    const float* vr = &sV[j*32];
    #pragma unroll
    for (int d=0; d<32; d+=4){
      float4 vv = *(const float4*)(vr+d);
      o[d]   = o[d]*ec   + e*vv.x;
      o[d+1] = o[d+1]*ec + e*vv.y;
      o[d+2] = o[d+2]*ec + e*vv.z;
      o[d+3] = o[d+3]*ec + e*vv.w;
    }
    m = mn;
  }
  float inv = 1.0f / l;
  float* orow = out + (long)pix*CCH + h*32;
  #pragma unroll
  for (int d=0; d<32; d+=4){
    float4 r; r.x=o[d]*inv; r.y=o[d+1]*inv; r.z=o[d+2]*inv; r.w=o[d+3]*inv;
    *(float4*)&orow[d] = r;
  }
}

// ---------------- output projection + window reverse -> NCHW f32 ------------
__global__ __launch_bounds__(256) void proj_kernel(
    const float* __restrict__ a,       // [65536][192] row-major
    const float* __restrict__ w,       // [192][192]
    const float* __restrict__ bias,
    float* __restrict__ outf)          // NCHW f32
{
  __shared__ float xs[96*68];
  __shared__ float wt[96*68];
  const int tid = threadIdx.x;
  const int pix0 = blockIdx.x * 64;
  const int bb = pix0 >> 14;
  const int hw0 = pix0 & (HWC-1);
  const long base = (long)bb * CCH * HWC + hw0;
  const int tp = tid & 15, tc = tid >> 4;

  float acc[3][4][4];
  #pragma unroll
  for (int coc=0; coc<3; coc++){
    #pragma unroll
    for (int u=0; u<4; u++){
      float bv = bias[coc*64 + tc*4 + u];
      #pragma unroll
      for (int v=0; v<4; v++) acc[coc][u][v] = bv;
    }
  }
  #pragma unroll
  for (int cic=0; cic<2; cic++){
    #pragma unroll
    for (int coc=0; coc<3; coc++){
      __syncthreads();
      if (coc == 0){
        #pragma unroll
        for (int i=0;i<24;i++){
          int idx = tid + i*256;
          int r = idx / 96, cil = idx - r*96;
          xs[cil*68 + r] = a[(long)(pix0 + r)*CCH + cic*96 + cil];
        }
      }
      #pragma unroll
      for (int i=0;i<24;i++){
        int idx = tid + i*256;
        int cc2 = idx / 96, cil = idx - cc2*96;
        wt[cil*68 + cc2] = w[(coc*64+cc2)*CCH + cic*96 + cil];
      }
      __syncthreads();
      #pragma unroll 2
      for (int cil=0; cil<96; cil++){
        float4 xv = *(const float4*)&xs[cil*68 + tp*4];
        float4 wv = *(const float4*)&wt[cil*68 + tc*4];
        float xa[4] = {xv.x, xv.y, xv.z, xv.w};
        float wa[4] = {wv.x, wv.y, wv.z, wv.w};
        #pragma unroll
        for (int u=0;u<4;u++)
          #pragma unroll
          for (int v=0;v<4;v++)
            acc[coc][u][v] = fmaf(wa[u], xa[v], acc[coc][u][v]);
      }
    }
  }
  #pragma unroll
  for (int coc=0; coc<3; coc++){
    #pragma unroll
    for (int u=0; u<4; u++){
      int co = coc*64 + tc*4 + u;
      long g = base + (long)co*HWC + tp*4;
      float4 r;
      r.x = acc[coc][u][0]; r.y = acc[coc][u][1];
      r.z = acc[coc][u][2]; r.w = acc[coc][u][3];
      *(float4*)&outf[g] = r;
    }
  }
}

// ---------------------------------------------------------------------------
extern "C" void kernel_launch(void* const* d_in, const int* in_sizes, int n_in,
                              void* d_out, int out_size, void* d_ws, size_t ws_size,
                              hipStream_t stream)
{
  const float* x       = (const float*)d_in[0];
  const float* p1_w    = (const float*)d_in[1];
  const float* p1_b    = (const float*)d_in[2];
  const float* pw_w    = (const float*)d_in[3];
  const float* pw_b    = (const float*)d_in[4];
  const float* dw_w    = (const float*)d_in[5];
  const float* dw_b    = (const float*)d_in[6];
  const float* dd_w    = (const float*)d_in[7];
  const float* dd_b    = (const float*)d_in[8];
  const float* p2_w    = (const float*)d_in[9];
  const float* p2_b    = (const float*)d_in[10];
  const float* ln_g    = (const float*)d_in[11];
  const float* ln_b    = (const float*)d_in[12];
  const float* qkv_w   = (const float*)d_in[13];
  const float* q_bias  = (const float*)d_in[14];
  const float* v_bias  = (const float*)d_in[15];
  const float* lscale  = (const float*)d_in[16];
  const float* cpb_w1  = (const float*)d_in[17];
  const float* cpb_b1  = (const float*)d_in[18];
  const float* cpb_w2  = (const float*)d_in[19];
  const float* proj_w  = (const float*)d_in[20];
  const float* proj_b  = (const float*)d_in[21];

  float* ws = (float*)d_ws;
  const long A = 12582912L;           // 4*192*128*128
  float* R0 = ws;                     // y (gelu)        ; later qkv[0..A)
  float* R1 = ws + A;                 // a / a3          ; later qkv[A..2A)
  float* R2 = ws + 2*A;               // dw tmp / y2     ; later qkv[2A..3A)
  float* R3 = ws + 3*A;               // z ; later attention output
  float* RB = ws + 4*A;               // bias table (6*256*256)
  float* T6 = RB + 393216;            // cpb mlp out (961*6)
  // total ws use: (4A + 393216 + 5766)*4 B ~= 194 MiB

  // CPB bias table (independent of main chain)
  cpb_mlp_kernel<<<961, 128, 0, stream>>>(cpb_w1, cpb_b1, cpb_w2, T6);
  cpb_expand_kernel<<<1536, 256, 0, stream>>>(T6, RB);

  // VAB conv block
  pw_kernel<0><<<1024, 256, 0, stream>>>(x, nullptr, nullptr, p1_w, p1_b, R0);
  pw_kernel<1><<<1024, 256, 0, stream>>>(nullptr, R0, nullptr, pw_w, pw_b, R1);
  dw_kernel<<<49152, 256, 0, stream>>>(R1, dw_w, dw_b, R2, 2, 1);
  dw_kernel<<<49152, 256, 0, stream>>>(R2, dd_w, dd_b, R1, 6, 3);
  pw_kernel<2><<<1024, 256, 0, stream>>>(x, R0, R1, p2_w, p2_b, R2);

  // LN -> z (NHWC row-major)
  ln_kernel<<<1024, 256, 0, stream>>>(R2, ln_g, ln_b, R3);

  // qkv GEMM (N split into 3 via grid.y)
  qkv_kernel<<<dim3(1024, 3), 256, 0, stream>>>(R3, qkv_w, q_bias, v_bias, R0);

  // window attention (z in R3 is dead now; reuse for attention output)
  attn_kernel<<<dim3(256, 6), 256, 0, stream>>>(R0, RB, lscale, R3);

  // projection + window reverse -> f32 NCHW
  proj_kernel<<<1024, 256, 0, stream>>>(R3, proj_w, proj_b, (float*)d_out);
}

// Round 3
// 1168.342 us; speedup vs baseline: 1.5823x; 1.5823x over previous
//
#include <hip/hip_runtime.h>
#include <hip/hip_bf16.h>
#include <math.h>

// Shapes: B=4, C=192, H=W=128, window 16 -> 256 windows of 256 tokens, 6 heads x 32
#define HWC 16384   // 128*128
#define CCH 192
#define LDA 200     // bf16 elems per LDS row (192 + 8 pad; 400 B, 16B-aligned rows)

typedef __attribute__((ext_vector_type(8))) short short8x;
typedef __attribute__((ext_vector_type(4))) float f32x4;

__device__ __forceinline__ unsigned short f2b(float f){
  union { float f; unsigned int i; } x; x.f = f;
  unsigned int r = x.i + 0x7FFFu + ((x.i >> 16) & 1u);   // RNE
  return (unsigned short)(r >> 16);
}
__device__ __forceinline__ float gelu_exact(float v){
  return 0.5f * v * (1.0f + erff(v * 0.70710678118654752440f));
}

// ---------------- weight cast fp32 -> bf16 (qkv_w 110592, proj_w 36864) -----
__global__ __launch_bounds__(256) void cast_w_kernel(
    const float* __restrict__ qkvw, const float* __restrict__ projw,
    unsigned short* __restrict__ wq, unsigned short* __restrict__ wp)
{
  int i = blockIdx.x*256 + threadIdx.x;
  if (i < 110592) wq[i] = f2b(qkvw[i]);
  if (i < 36864)  wp[i] = f2b(projw[i]);
}

// ---------------- pointwise 1x1 conv (NCHW), register-tiled GEMM -------------
// MODE 0: in = xres (x), out = gelu(conv)
// MODE 1: in = inA, out = conv
// MODE 2: in = inA*inB, out = conv + residual xres
template<int MODE>
__global__ __launch_bounds__(256) void pw_kernel(
    const float* __restrict__ xres,
    const float* __restrict__ inA,
    const float* __restrict__ inB,
    const float* __restrict__ w,     // [co][ci]
    const float* __restrict__ bias,  // [co]
    float* __restrict__ out)
{
  __shared__ float xs[96*68];
  __shared__ float wt[96*68];
  const int tid = threadIdx.x;
  const int pix0 = blockIdx.x * 64;
  const int bb = pix0 >> 14;
  const int hw0 = pix0 & (HWC-1);
  const long base = (long)bb * CCH * HWC + hw0;
  const int tp = tid & 15, tc = tid >> 4;

  float acc[3][4][4];
  #pragma unroll
  for (int coc=0; coc<3; coc++){
    #pragma unroll
    for (int u=0; u<4; u++){
      float bv = bias[coc*64 + tc*4 + u];
      #pragma unroll
      for (int v=0; v<4; v++) acc[coc][u][v] = bv;
    }
  }
  #pragma unroll
  for (int cic=0; cic<2; cic++){
    #pragma unroll
    for (int coc=0; coc<3; coc++){
      __syncthreads();
      if (coc == 0){
        #pragma unroll
        for (int i=0;i<24;i++){
          int idx = tid + i*256;
          int cil = idx >> 6, pix = idx & 63;
          long g = base + (long)(cic*96 + cil)*HWC + pix;
          float v;
          if (MODE==0)      v = xres[g];
          else if (MODE==1) v = inA[g];
          else              v = inA[g]*inB[g];
          xs[cil*68 + pix] = v;
        }
      }
      #pragma unroll
      for (int i=0;i<24;i++){
        int idx = tid + i*256;
        int cc2 = idx / 96, cil = idx - cc2*96;
        wt[cil*68 + cc2] = w[(coc*64+cc2)*CCH + cic*96 + cil];
      }
      __syncthreads();
      #pragma unroll 2
      for (int cil=0; cil<96; cil++){
        float4 xv = *(const float4*)&xs[cil*68 + tp*4];
        float4 wv = *(const float4*)&wt[cil*68 + tc*4];
        float xa[4] = {xv.x, xv.y, xv.z, xv.w};
        float wa[4] = {wv.x, wv.y, wv.z, wv.w};
        #pragma unroll
        for (int u=0;u<4;u++)
          #pragma unroll
          for (int v=0;v<4;v++)
            acc[coc][u][v] = fmaf(wa[u], xa[v], acc[coc][u][v]);
      }
    }
  }
  #pragma unroll
  for (int coc=0; coc<3; coc++){
    #pragma unroll
    for (int u=0; u<4; u++){
      int co = coc*64 + tc*4 + u;
      long g = base + (long)co*HWC + tp*4;
      float t0 = acc[coc][u][0], t1 = acc[coc][u][1];
      float t2 = acc[coc][u][2], t3 = acc[coc][u][3];
      if (MODE==0){ t0=gelu_exact(t0); t1=gelu_exact(t1); t2=gelu_exact(t2); t3=gelu_exact(t3); }
      if (MODE==2){
        float4 rv = *(const float4*)&xres[g];
        t0 += rv.x; t1 += rv.y; t2 += rv.z; t3 += rv.w;
      }
      float4 r; r.x=t0; r.y=t1; r.z=t2; r.w=t3;
      *(float4*)&out[g] = r;
    }
  }
}

// ---------------- depthwise 5x5 conv (generic pad/dil), NCHW f32 ------------
__global__ __launch_bounds__(256) void dw_kernel(
    const float* __restrict__ in, const float* __restrict__ w,
    const float* __restrict__ bias, float* __restrict__ out,
    int pad, int dil)
{
  int idx = blockIdx.x*256 + threadIdx.x;
  int wx = idx & 127;
  int hy = (idx >> 7) & 127;
  int bc = idx >> 14;            // b*192 + c
  int c  = bc % 192;
  const float* ib = in + (long)bc * HWC;
  float acc = bias[c];
  #pragma unroll
  for (int kh=0; kh<5; kh++){
    int ih = hy + kh*dil - pad;
    if ((unsigned)ih < 128u){
      const float* irow = ib + ih*128;
      #pragma unroll
      for (int kw=0; kw<5; kw++){
        int iw = wx + kw*dil - pad;
        if ((unsigned)iw < 128u)
          acc = fmaf(w[c*25 + kh*5 + kw], irow[iw], acc);
      }
    }
  }
  out[idx] = acc;
}

// -------- LayerNorm over C, NCHW f32 -> NHWC *bf16* (z16, K-contiguous) -----
__global__ __launch_bounds__(256) void ln_kernel(
    const float* __restrict__ in, const float* __restrict__ gam,
    const float* __restrict__ bet, unsigned short* __restrict__ z16)
{
  __shared__ float xs[CCH*68];
  __shared__ float ps[4*64], ps2[4*64], smu[64], srs[64];
  const int tid = threadIdx.x;
  const int pix0 = blockIdx.x * 64;
  const int bb = pix0 >> 14;
  const int hw0 = pix0 & (HWC-1);
  const long base = (long)bb * CCH * HWC + hw0;
  #pragma unroll 8
  for (int i=0;i<48;i++){
    int idx = tid + i*256;
    int ci = idx >> 6, pix = idx & 63;
    xs[ci*68 + pix] = in[base + (long)ci*HWC + pix];
  }
  __syncthreads();
  {
    int pix = tid & 63, g = tid >> 6;
    float s=0.f, s2=0.f;
    for (int ci=g*48; ci<g*48+48; ci++){
      float v = xs[ci*68 + pix]; s += v; s2 = fmaf(v, v, s2);
    }
    ps[g*64+pix] = s; ps2[g*64+pix] = s2;
  }
  __syncthreads();
  if (tid < 64){
    float s  = ps[tid]  + ps[64+tid]  + ps[128+tid]  + ps[192+tid];
    float s2 = ps2[tid] + ps2[64+tid] + ps2[128+tid] + ps2[192+tid];
    float mu = s * (1.0f/192.0f);
    float var = s2 * (1.0f/192.0f) - mu*mu;
    smu[tid] = mu;
    srs[tid] = rsqrtf(var + 1e-5f);
  }
  __syncthreads();
  #pragma unroll 8
  for (int i=0;i<48;i++){
    int idx = tid + i*256;
    int pix = idx / 192, ci = idx - pix*192;
    float v = (xs[ci*68 + pix] - smu[pix]) * srs[pix] * gam[ci] + bet[ci];
    z16[(long)(pix0 + pix)*CCH + ci] = f2b(v);
  }
}

// ---------------- qkv GEMM via MFMA: z16[65536][192] @ WQ^T -> qkv f32 ------
// A = activations (M=pix), B = weights (N=co). C[m=pix][n=co]:
// 16x16x32_bf16 layouts: A[m=lane&15][k=quad*8+j]; B[n=lane&15][k=quad*8+j];
// C col=lane&15(n), row=quad*4+reg(m).  [verified m89/m91]
__global__ __launch_bounds__(256, 3) void qkv_mfma(
    const unsigned short* __restrict__ z16,   // [65536][192] bf16
    const unsigned short* __restrict__ w16,   // [576][192] bf16
    const float* __restrict__ qb, const float* __restrict__ vb,
    float* __restrict__ qkv)                  // [65536][576] f32
{
  __shared__ unsigned short sA[128*LDA];      // 51200 B
  const int tid = threadIdx.x;
  const int m0 = blockIdx.x * 128;            // pixel base
  const int s  = blockIdx.y;                  // 0=q,1=k,2=v
  // stage A: 128 rows x 24 octs of 8 bf16 (16 B)
  #pragma unroll
  for (int i=0;i<12;i++){
    int idx = tid + i*256;
    int row = idx / 24, oct = idx - row*24;
    uint4 v = *(const uint4*)(z16 + (long)(m0+row)*CCH + oct*8);
    *(uint4*)&sA[row*LDA + oct*8] = v;
  }
  __syncthreads();
  const int wv = tid >> 6, lane = tid & 63;
  const int wm = (wv & 1) * 64;               // pix offset in tile
  const int wn = (wv >> 1) * 96;              // co offset in slice
  const int l15 = lane & 15, q = lane >> 4;
  const unsigned short* wbase = w16 + (long)(s*192)*CCH;
  f32x4 acc[4][6];
  #pragma unroll
  for (int mi=0;mi<4;mi++)
    #pragma unroll
    for (int ni=0;ni<6;ni++) acc[mi][ni] = (f32x4){0.f,0.f,0.f,0.f};
  #pragma unroll
  for (int kk=0; kk<6; kk++){
    const int k0 = kk*32;
    short8x af[4], bf[6];
    #pragma unroll
    for (int mi=0; mi<4; mi++)
      af[mi] = *(const short8x*)&sA[(wm + mi*16 + l15)*LDA + k0 + q*8];
    #pragma unroll
    for (int ni=0; ni<6; ni++)
      bf[ni] = *(const short8x*)(wbase + (long)(wn + ni*16 + l15)*CCH + k0 + q*8);
    #pragma unroll
    for (int mi=0; mi<4; mi++)
      #pragma unroll
      for (int ni=0; ni<6; ni++)
        acc[mi][ni] = __builtin_amdgcn_mfma_f32_16x16x32_bf16(af[mi], bf[ni], acc[mi][ni], 0,0,0);
  }
  #pragma unroll
  for (int ni=0; ni<6; ni++){
    int co = wn + ni*16 + l15;                // 0..191 within slice
    float bv = (s==0) ? qb[co] : ((s==2) ? vb[co] : 0.0f);
    #pragma unroll
    for (int mi=0; mi<4; mi++){
      #pragma unroll
      for (int r=0; r<4; r++){
        int pix = m0 + wm + mi*16 + q*4 + r;
        qkv[(long)pix*576 + s*192 + co] = acc[mi][ni][r] + bv;
      }
    }
  }
}

// ---------------- CPB MLP: table(961,2) -> (961,6) --------------------------
__device__ __forceinline__ float cpb_coord(int a){
  float r = ((float)a - 15.0f) * (8.0f/15.0f);
  float t = log2f(fabsf(r) + 1.0f) * (1.0f/3.0f);
  return (r < 0.f) ? -t : t;
}
__global__ __launch_bounds__(128) void cpb_mlp_kernel(
    const float* __restrict__ w1, const float* __restrict__ b1,
    const float* __restrict__ w2, float* __restrict__ tbl6)
{
  int e = blockIdx.x;
  int a = e / 31, bb = e - a*31;
  float t0 = cpb_coord(a), t1 = cpb_coord(bb);
  float p[6] = {0,0,0,0,0,0};
  for (int hh = threadIdx.x; hh < 512; hh += 128){
    float hid = t0*w1[hh*2] + t1*w1[hh*2+1] + b1[hh];
    hid = fmaxf(hid, 0.0f);
    #pragma unroll
    for (int hd=0; hd<6; hd++) p[hd] = fmaf(hid, w2[hd*512 + hh], p[hd]);
  }
  __shared__ float red[6][128];
  #pragma unroll
  for (int hd=0; hd<6; hd++) red[hd][threadIdx.x] = p[hd];
  __syncthreads();
  if (threadIdx.x < 6){
    float sum = 0.f;
    for (int i=0;i<128;i++) sum += red[threadIdx.x][i];
    tbl6[e*6 + threadIdx.x] = sum;
  }
}
// expand to bias[h][i][j] = 16*sigmoid(tbl6[relidx(i,j)][h])
__global__ __launch_bounds__(256) void cpb_expand_kernel(
    const float* __restrict__ tbl6, float* __restrict__ bias)
{
  int idx = blockIdx.x*256 + threadIdx.x;      // < 6*256*256
  int h = idx >> 16;
  int rem = idx & 65535;
  int i = rem >> 8, j = rem & 255;
  int dy = (i>>4) - (j>>4) + 15;
  int dx = (i&15) - (j&15) + 15;
  float v = tbl6[(dy*31+dx)*6 + h];
  bias[idx] = 16.0f / (1.0f + __expf(-v));
}

// ---------------- windowed cosine attention, one block per (win, head) ------
__global__ __launch_bounds__(256) void attn_kernel(
    const float* __restrict__ qkv, const float* __restrict__ bias,
    const float* __restrict__ ls, unsigned short* __restrict__ aout)
{
  __shared__ float sK[256*32];   // 32 KB
  __shared__ float sV[256*32];   // 32 KB
  const int win = blockIdx.x, h = blockIdx.y;
  const int t = threadIdx.x;
  const int bb = win >> 6;
  const int wy = (win >> 3) & 7, wx = win & 7;
  const int ty = t >> 4, tx = t & 15;
  const int pix = bb*HWC + (wy*16+ty)*128 + wx*16 + tx;
  const float* row = qkv + (long)pix*576 + h*32;
  float q[32];
  float sq = 0.f, sk = 0.f;
  #pragma unroll
  for (int d=0; d<32; d+=4){
    float4 qv = *(const float4*)(row + d);
    float4 kv = *(const float4*)(row + 192 + d);
    float4 vv = *(const float4*)(row + 384 + d);
    q[d]=qv.x; q[d+1]=qv.y; q[d+2]=qv.z; q[d+3]=qv.w;
    sq += qv.x*qv.x + qv.y*qv.y + qv.z*qv.z + qv.w*qv.w;
    sk += kv.x*kv.x + kv.y*kv.y + kv.z*kv.z + kv.w*kv.w;
    *(float4*)&sK[t*32+d] = kv;
    *(float4*)&sV[t*32+d] = vv;
  }
  float sc = __expf(fminf(ls[h], 4.60517018598809136804f));  // ln(100)
  float qinv = sc / fmaxf(sqrtf(sq), 1e-12f);
  float kinv = 1.0f / fmaxf(sqrtf(sk), 1e-12f);
  #pragma unroll
  for (int d=0; d<32; d++) q[d] *= qinv;
  #pragma unroll
  for (int d=0; d<32; d+=4){
    float4 kv = *(float4*)&sK[t*32+d];
    kv.x*=kinv; kv.y*=kinv; kv.z*=kinv; kv.w*=kinv;
    *(float4*)&sK[t*32+d] = kv;
  }
  __syncthreads();
  const float* brow = bias + (((h<<8) + t) << 8);   // h*65536 + t*256
  float m = -1e30f, l = 0.f;
  float o[32];
  #pragma unroll
  for (int d=0; d<32; d++) o[d] = 0.f;
  for (int j=0; j<256; j++){
    const float* kr = &sK[j*32];
    float s = 0.f;
    #pragma unroll
    for (int d=0; d<32; d+=4){
      float4 kv = *(const float4*)(kr+d);
      s += q[d]*kv.x + q[d+1]*kv.y + q[d+2]*kv.z + q[d+3]*kv.w;
    }
    s += brow[j];
    float mn = fmaxf(m, s);
    float ec = __expf(m - mn);
    float e  = __expf(s - mn);
    l = l*ec + e;
    const float* vr = &sV[j*32];
    #pragma unroll
    for (int d=0; d<32; d+=4){
      float4 vv = *(const float4*)(vr+d);
      o[d]   = o[d]*ec   + e*vv.x;
      o[d+1] = o[d+1]*ec + e*vv.y;
      o[d+2] = o[d+2]*ec + e*vv.z;
      o[d+3] = o[d+3]*ec + e*vv.w;
    }
    m = mn;
  }
  float inv = 1.0f / l;
  unsigned short* orow = aout + (long)pix*CCH + h*32;
  #pragma unroll
  for (int d=0; d<32; d+=4){
    ushort4 st;
    st.x = f2b(o[d]*inv);   st.y = f2b(o[d+1]*inv);
    st.z = f2b(o[d+2]*inv); st.w = f2b(o[d+3]*inv);
    *(ushort4*)&orow[d] = st;
  }
}

// ------- proj GEMM via MFMA: aout16 @ WP^T + b -> NCHW f32 (coalesced) ------
// A = weights (M=co), B = activations (N=pix). C[m=co][n=pix]:
// store (co, q*4+r ; pix = lane&15) -> 16 consecutive pix = 64 B contiguous.
__global__ __launch_bounds__(256, 3) void proj_mfma(
    const unsigned short* __restrict__ a16,   // [65536][192] bf16
    const unsigned short* __restrict__ w16,   // [192][192] bf16
    const float* __restrict__ bias,
    float* __restrict__ outp)                 // NCHW f32
{
  __shared__ unsigned short sB[128*LDA];
  const int tid = threadIdx.x;
  const int n0 = blockIdx.x * 128;            // pixel base
  #pragma unroll
  for (int i=0;i<12;i++){
    int idx = tid + i*256;
    int row = idx / 24, oct = idx - row*24;
    uint4 v = *(const uint4*)(a16 + (long)(n0+row)*CCH + oct*8);
    *(uint4*)&sB[row*LDA + oct*8] = v;
  }
  __syncthreads();
  const int wv = tid >> 6, lane = tid & 63;
  const int wm = (wv & 1) * 96;               // co offset
  const int wn = (wv >> 1) * 64;              // pix offset in tile
  const int l15 = lane & 15, q = lane >> 4;
  f32x4 acc[6][4];
  #pragma unroll
  for (int mi=0;mi<6;mi++)
    #pragma unroll
    for (int ni=0;ni<4;ni++) acc[mi][ni] = (f32x4){0.f,0.f,0.f,0.f};
  #pragma unroll
  for (int kk=0; kk<6; kk++){
    const int k0 = kk*32;
    short8x af[6], bf[4];
    #pragma unroll
    for (int mi=0; mi<6; mi++)
      af[mi] = *(const short8x*)(w16 + (long)(wm + mi*16 + l15)*CCH + k0 + q*8);
    #pragma unroll
    for (int ni=0; ni<4; ni++)
      bf[ni] = *(const short8x*)&sB[(wn + ni*16 + l15)*LDA + k0 + q*8];
    #pragma unroll
    for (int mi=0; mi<6; mi++)
      #pragma unroll
      for (int ni=0; ni<4; ni++)
        acc[mi][ni] = __builtin_amdgcn_mfma_f32_16x16x32_bf16(af[mi], bf[ni], acc[mi][ni], 0,0,0);
  }
  #pragma unroll
  for (int mi=0; mi<6; mi++){
    #pragma unroll
    for (int r=0; r<4; r++){
      int co = wm + mi*16 + q*4 + r;
      float bv = bias[co];
      #pragma unroll
      for (int ni=0; ni<4; ni++){
        int pix = n0 + wn + ni*16 + l15;
        int b = pix >> 14, hw = pix & (HWC-1);
        outp[((long)b*CCH + co)*HWC + hw] = acc[mi][ni][r] + bv;
      }
    }
  }
}

// ---------------------------------------------------------------------------
extern "C" void kernel_launch(void* const* d_in, const int* in_sizes, int n_in,
                              void* d_out, int out_size, void* d_ws, size_t ws_size,
                              hipStream_t stream)
{
  const float* x       = (const float*)d_in[0];
  const float* p1_w    = (const float*)d_in[1];
  const float* p1_b    = (const float*)d_in[2];
  const float* pw_w    = (const float*)d_in[3];
  const float* pw_b    = (const float*)d_in[4];
  const float* dw_w    = (const float*)d_in[5];
  const float* dw_b    = (const float*)d_in[6];
  const float* dd_w    = (const float*)d_in[7];
  const float* dd_b    = (const float*)d_in[8];
  const float* p2_w    = (const float*)d_in[9];
  const float* p2_b    = (const float*)d_in[10];
  const float* ln_g    = (const float*)d_in[11];
  const float* ln_b    = (const float*)d_in[12];
  const float* qkv_w   = (const float*)d_in[13];
  const float* q_bias  = (const float*)d_in[14];
  const float* v_bias  = (const float*)d_in[15];
  const float* lscale  = (const float*)d_in[16];
  const float* cpb_w1  = (const float*)d_in[17];
  const float* cpb_b1  = (const float*)d_in[18];
  const float* cpb_w2  = (const float*)d_in[19];
  const float* proj_w  = (const float*)d_in[20];
  const float* proj_b  = (const float*)d_in[21];

  float* ws = (float*)d_ws;
  const long A = 12582912L;           // 4*192*128*128
  float* R0 = ws;                     // y ; later qkv f32 spans R0..R2 (3A)
  float* R1 = ws + A;                 // a / a3
  float* R2 = ws + 2*A;               // dw tmp / y2
  // R3 region [3A,4A): first half = z16 (later reused as attn-out bf16),
  // second half holds bf16 weights. Same total footprint as round 2.
  unsigned short* Z16  = (unsigned short*)(ws + 3*A);   // A ushorts (= A/2 floats)
  unsigned short* AO16 = Z16;                           // attn out reuses z16 space
  unsigned short* WQ   = (unsigned short*)(ws + 3*A + A/2);        // 110592
  unsigned short* WP   = WQ + 110592;                               // 36864
  float* RB = ws + 4*A;               // bias table (6*256*256)
  float* T6 = RB + 393216;            // cpb mlp out (961*6)

  // weight casts + CPB bias table (independent of main chain)
  cast_w_kernel<<<432, 256, 0, stream>>>(qkv_w, proj_w, WQ, WP);
  cpb_mlp_kernel<<<961, 128, 0, stream>>>(cpb_w1, cpb_b1, cpb_w2, T6);
  cpb_expand_kernel<<<1536, 256, 0, stream>>>(T6, RB);

  // VAB conv block (fp32 scalar path, unchanged)
  pw_kernel<0><<<1024, 256, 0, stream>>>(x, nullptr, nullptr, p1_w, p1_b, R0);
  pw_kernel<1><<<1024, 256, 0, stream>>>(nullptr, R0, nullptr, pw_w, pw_b, R1);
  dw_kernel<<<49152, 256, 0, stream>>>(R1, dw_w, dw_b, R2, 2, 1);
  dw_kernel<<<49152, 256, 0, stream>>>(R2, dd_w, dd_b, R1, 6, 3);
  pw_kernel<2><<<1024, 256, 0, stream>>>(x, R0, R1, p2_w, p2_b, R2);

  // LN -> z bf16 (NHWC row-major, K-contiguous)
  ln_kernel<<<1024, 256, 0, stream>>>(R2, ln_g, ln_b, Z16);

  // qkv GEMM on MFMA (y/a3/y2 all dead -> qkv f32 occupies R0..R2)
  qkv_mfma<<<dim3(512, 3), 256, 0, stream>>>(Z16, WQ, q_bias, v_bias, R0);

  // window attention (fp32 math, bf16 out; z16 dead -> reuse as AO16)
  attn_kernel<<<dim3(256, 6), 256, 0, stream>>>(R0, RB, lscale, AO16);

  // projection on MFMA + window-reverse -> f32 NCHW
  proj_mfma<<<512, 256, 0, stream>>>(AO16, WP, proj_b, (float*)d_out);
}

// Round 4
// 960.777 us; speedup vs baseline: 1.9241x; 1.2160x over previous
//
#include <hip/hip_runtime.h>
#include <hip/hip_bf16.h>
#include <math.h>

// Shapes: B=4, C=192, H=W=128, window 16 -> 256 windows of 256 tokens, 6 heads x 32
#define HWC 16384   // 128*128
#define CCH 192
#define LDA 200     // bf16 elems per LDS row (192 + 8 pad; 400 B, 16B-aligned rows)

typedef __attribute__((ext_vector_type(8))) short short8x;
typedef __attribute__((ext_vector_type(4))) float f32x4;

__device__ __forceinline__ unsigned short f2b(float f){
  union { float f; unsigned int i; } x; x.f = f;
  unsigned int r = x.i + 0x7FFFu + ((x.i >> 16) & 1u);   // RNE
  return (unsigned short)(r >> 16);
}
__device__ __forceinline__ float gelu_exact(float v){
  return 0.5f * v * (1.0f + erff(v * 0.70710678118654752440f));
}

// ---------------- weight cast fp32 -> bf16 (qkv_w 110592, proj_w 36864) -----
__global__ __launch_bounds__(256) void cast_w_kernel(
    const float* __restrict__ qkvw, const float* __restrict__ projw,
    unsigned short* __restrict__ wq, unsigned short* __restrict__ wp)
{
  int i = blockIdx.x*256 + threadIdx.x;
  if (i < 110592) wq[i] = f2b(qkvw[i]);
  if (i < 36864)  wp[i] = f2b(projw[i]);
}

// ---------------- pointwise 1x1 conv (NCHW), register-tiled GEMM -------------
template<int MODE>
__global__ __launch_bounds__(256) void pw_kernel(
    const float* __restrict__ xres,
    const float* __restrict__ inA,
    const float* __restrict__ inB,
    const float* __restrict__ w,     // [co][ci]
    const float* __restrict__ bias,  // [co]
    float* __restrict__ out)
{
  __shared__ float xs[96*68];
  __shared__ float wt[96*68];
  const int tid = threadIdx.x;
  const int pix0 = blockIdx.x * 64;
  const int bb = pix0 >> 14;
  const int hw0 = pix0 & (HWC-1);
  const long base = (long)bb * CCH * HWC + hw0;
  const int tp = tid & 15, tc = tid >> 4;

  float acc[3][4][4];
  #pragma unroll
  for (int coc=0; coc<3; coc++){
    #pragma unroll
    for (int u=0; u<4; u++){
      float bv = bias[coc*64 + tc*4 + u];
      #pragma unroll
      for (int v=0; v<4; v++) acc[coc][u][v] = bv;
    }
  }
  #pragma unroll
  for (int cic=0; cic<2; cic++){
    #pragma unroll
    for (int coc=0; coc<3; coc++){
      __syncthreads();
      if (coc == 0){
        #pragma unroll
        for (int i=0;i<24;i++){
          int idx = tid + i*256;
          int cil = idx >> 6, pix = idx & 63;
          long g = base + (long)(cic*96 + cil)*HWC + pix;
          float v;
          if (MODE==0)      v = xres[g];
          else if (MODE==1) v = inA[g];
          else              v = inA[g]*inB[g];
          xs[cil*68 + pix] = v;
        }
      }
      #pragma unroll
      for (int i=0;i<24;i++){
        int idx = tid + i*256;
        int cc2 = idx / 96, cil = idx - cc2*96;
        wt[cil*68 + cc2] = w[(coc*64+cc2)*CCH + cic*96 + cil];
      }
      __syncthreads();
      #pragma unroll 2
      for (int cil=0; cil<96; cil++){
        float4 xv = *(const float4*)&xs[cil*68 + tp*4];
        float4 wv = *(const float4*)&wt[cil*68 + tc*4];
        float xa[4] = {xv.x, xv.y, xv.z, xv.w};
        float wa[4] = {wv.x, wv.y, wv.z, wv.w};
        #pragma unroll
        for (int u=0;u<4;u++)
          #pragma unroll
          for (int v=0;v<4;v++)
            acc[coc][u][v] = fmaf(wa[u], xa[v], acc[coc][u][v]);
      }
    }
  }
  #pragma unroll
  for (int coc=0; coc<3; coc++){
    #pragma unroll
    for (int u=0; u<4; u++){
      int co = coc*64 + tc*4 + u;
      long g = base + (long)co*HWC + tp*4;
      float t0 = acc[coc][u][0], t1 = acc[coc][u][1];
      float t2 = acc[coc][u][2], t3 = acc[coc][u][3];
      if (MODE==0){ t0=gelu_exact(t0); t1=gelu_exact(t1); t2=gelu_exact(t2); t3=gelu_exact(t3); }
      if (MODE==2){
        float4 rv = *(const float4*)&xres[g];
        t0 += rv.x; t1 += rv.y; t2 += rv.z; t3 += rv.w;
      }
      float4 r; r.x=t0; r.y=t1; r.z=t2; r.w=t3;
      *(float4*)&out[g] = r;
    }
  }
}

// ---------------- depthwise 5x5 conv (generic pad/dil), NCHW f32 ------------
__global__ __launch_bounds__(256) void dw_kernel(
    const float* __restrict__ in, const float* __restrict__ w,
    const float* __restrict__ bias, float* __restrict__ out,
    int pad, int dil)
{
  int idx = blockIdx.x*256 + threadIdx.x;
  int wx = idx & 127;
  int hy = (idx >> 7) & 127;
  int bc = idx >> 14;            // b*192 + c
  int c  = bc % 192;
  const float* ib = in + (long)bc * HWC;
  float acc = bias[c];
  #pragma unroll
  for (int kh=0; kh<5; kh++){
    int ih = hy + kh*dil - pad;
    if ((unsigned)ih < 128u){
      const float* irow = ib + ih*128;
      #pragma unroll
      for (int kw=0; kw<5; kw++){
        int iw = wx + kw*dil - pad;
        if ((unsigned)iw < 128u)
          acc = fmaf(w[c*25 + kh*5 + kw], irow[iw], acc);
      }
    }
  }
  out[idx] = acc;
}

// -------- LayerNorm over C, NCHW f32 -> NHWC *bf16* (z16, K-contiguous) -----
__global__ __launch_bounds__(256) void ln_kernel(
    const float* __restrict__ in, const float* __restrict__ gam,
    const float* __restrict__ bet, unsigned short* __restrict__ z16)
{
  __shared__ float xs[CCH*68];
  __shared__ float ps[4*64], ps2[4*64], smu[64], srs[64];
  const int tid = threadIdx.x;
  const int pix0 = blockIdx.x * 64;
  const int bb = pix0 >> 14;
  const int hw0 = pix0 & (HWC-1);
  const long base = (long)bb * CCH * HWC + hw0;
  #pragma unroll 8
  for (int i=0;i<48;i++){
    int idx = tid + i*256;
    int ci = idx >> 6, pix = idx & 63;
    xs[ci*68 + pix] = in[base + (long)ci*HWC + pix];
  }
  __syncthreads();
  {
    int pix = tid & 63, g = tid >> 6;
    float s=0.f, s2=0.f;
    for (int ci=g*48; ci<g*48+48; ci++){
      float v = xs[ci*68 + pix]; s += v; s2 = fmaf(v, v, s2);
    }
    ps[g*64+pix] = s; ps2[g*64+pix] = s2;
  }
  __syncthreads();
  if (tid < 64){
    float s  = ps[tid]  + ps[64+tid]  + ps[128+tid]  + ps[192+tid];
    float s2 = ps2[tid] + ps2[64+tid] + ps2[128+tid] + ps2[192+tid];
    float mu = s * (1.0f/192.0f);
    float var = s2 * (1.0f/192.0f) - mu*mu;
    smu[tid] = mu;
    srs[tid] = rsqrtf(var + 1e-5f);
  }
  __syncthreads();
  #pragma unroll 8
  for (int i=0;i<48;i++){
    int idx = tid + i*256;
    int pix = idx / 192, ci = idx - pix*192;
    float v = (xs[ci*68 + pix] - smu[pix]) * srs[pix] * gam[ci] + bet[ci];
    z16[(long)(pix0 + pix)*CCH + ci] = f2b(v);
  }
}

// ---------------- qkv GEMM via MFMA: z16[65536][192] @ WQ^T -> qkv f32 ------
__global__ __launch_bounds__(256, 3) void qkv_mfma(
    const unsigned short* __restrict__ z16,   // [65536][192] bf16
    const unsigned short* __restrict__ w16,   // [576][192] bf16
    const float* __restrict__ qb, const float* __restrict__ vb,
    float* __restrict__ qkv)                  // [65536][576] f32
{
  __shared__ unsigned short sA[128*LDA];      // 51200 B
  const int tid = threadIdx.x;
  const int m0 = blockIdx.x * 128;            // pixel base
  const int s  = blockIdx.y;                  // 0=q,1=k,2=v
  #pragma unroll
  for (int i=0;i<12;i++){
    int idx = tid + i*256;
    int row = idx / 24, oct = idx - row*24;
    uint4 v = *(const uint4*)(z16 + (long)(m0+row)*CCH + oct*8);
    *(uint4*)&sA[row*LDA + oct*8] = v;
  }
  __syncthreads();
  const int wv = tid >> 6, lane = tid & 63;
  const int wm = (wv & 1) * 64;               // pix offset in tile
  const int wn = (wv >> 1) * 96;              // co offset in slice
  const int l15 = lane & 15, q = lane >> 4;
  const unsigned short* wbase = w16 + (long)(s*192)*CCH;
  f32x4 acc[4][6];
  #pragma unroll
  for (int mi=0;mi<4;mi++)
    #pragma unroll
    for (int ni=0;ni<6;ni++) acc[mi][ni] = (f32x4){0.f,0.f,0.f,0.f};
  #pragma unroll
  for (int kk=0; kk<6; kk++){
    const int k0 = kk*32;
    short8x af[4], bf[6];
    #pragma unroll
    for (int mi=0; mi<4; mi++)
      af[mi] = *(const short8x*)&sA[(wm + mi*16 + l15)*LDA + k0 + q*8];
    #pragma unroll
    for (int ni=0; ni<6; ni++)
      bf[ni] = *(const short8x*)(wbase + (long)(wn + ni*16 + l15)*CCH + k0 + q*8);
    #pragma unroll
    for (int mi=0; mi<4; mi++)
      #pragma unroll
      for (int ni=0; ni<6; ni++)
        acc[mi][ni] = __builtin_amdgcn_mfma_f32_16x16x32_bf16(af[mi], bf[ni], acc[mi][ni], 0,0,0);
  }
  #pragma unroll
  for (int ni=0; ni<6; ni++){
    int co = wn + ni*16 + l15;                // 0..191 within slice
    float bv = (s==0) ? qb[co] : ((s==2) ? vb[co] : 0.0f);
    #pragma unroll
    for (int mi=0; mi<4; mi++){
      #pragma unroll
      for (int r=0; r<4; r++){
        int pix = m0 + wm + mi*16 + q*4 + r;
        qkv[(long)pix*576 + s*192 + co] = acc[mi][ni][r] + bv;
      }
    }
  }
}

// ---------------- CPB MLP: table(961,2) -> (961,6) --------------------------
__device__ __forceinline__ float cpb_coord(int a){
  float r = ((float)a - 15.0f) * (8.0f/15.0f);
  float t = log2f(fabsf(r) + 1.0f) * (1.0f/3.0f);
  return (r < 0.f) ? -t : t;
}
__global__ __launch_bounds__(128) void cpb_mlp_kernel(
    const float* __restrict__ w1, const float* __restrict__ b1,
    const float* __restrict__ w2, float* __restrict__ tbl6)
{
  int e = blockIdx.x;
  int a = e / 31, bb = e - a*31;
  float t0 = cpb_coord(a), t1 = cpb_coord(bb);
  float p[6] = {0,0,0,0,0,0};
  for (int hh = threadIdx.x; hh < 512; hh += 128){
    float hid = t0*w1[hh*2] + t1*w1[hh*2+1] + b1[hh];
    hid = fmaxf(hid, 0.0f);
    #pragma unroll
    for (int hd=0; hd<6; hd++) p[hd] = fmaf(hid, w2[hd*512 + hh], p[hd]);
  }
  __shared__ float red[6][128];
  #pragma unroll
  for (int hd=0; hd<6; hd++) red[hd][threadIdx.x] = p[hd];
  __syncthreads();
  if (threadIdx.x < 6){
    float sum = 0.f;
    for (int i=0;i<128;i++) sum += red[threadIdx.x][i];
    tbl6[e*6 + threadIdx.x] = sum;
  }
}
// expand to bias[h][i][j] = 16*sigmoid(tbl6[relidx(i,j)][h]) - 16  (shift folded
// in so attention exponents are <= 10: softmax is shift-invariant)
__global__ __launch_bounds__(256) void cpb_expand_kernel(
    const float* __restrict__ tbl6, float* __restrict__ bias)
{
  int idx = blockIdx.x*256 + threadIdx.x;      // < 6*256*256
  int h = idx >> 16;
  int rem = idx & 65535;
  int i = rem >> 8, j = rem & 255;
  int dy = (i>>4) - (j>>4) + 15;
  int dx = (i&15) - (j&15) + 15;
  float v = tbl6[(dy*31+dx)*6 + h];
  bias[idx] = 16.0f / (1.0f + __expf(-v)) - 16.0f;
}

// ------------- windowed cosine attention via MFMA, block=(win, head) --------
// 4 waves x 64 queries; key tiles of 32; no online softmax (logits <= 10 after
// the folded -16 bias shift). P round-trips wave-private LDS (C->A layout).
#define KSP 40    // ks/qs/ps row stride (shorts): 80 B, 16B-aligned, 2-way banks
#define VTP 264   // vt row stride (shorts): 528 B, 16B-aligned, 2-way banks
__global__ __launch_bounds__(256) void attn_mfma(
    const float* __restrict__ qkv, const float* __restrict__ bias,
    const float* __restrict__ ls, unsigned short* __restrict__ aout)
{
  __shared__ unsigned short ks[256*KSP];      // 20480 B  kn bf16 [key][d]
  __shared__ unsigned short vt[32*VTP];       // 16896 B  v bf16 [d][key]
  __shared__ unsigned short ps[4][64*KSP];    // 20480 B  per-wave P / (init: qs)
  unsigned short* qs = &ps[0][0];             // 256*40 shorts = 10240 fits 4*2560

  const int win = blockIdx.x, h = blockIdx.y;
  const int t = threadIdx.x;
  const int bb = win >> 6;
  const int wy = (win >> 3) & 7, wx = win & 7;
  const float sc = __expf(fminf(ls[h], 4.60517018598809136804f));  // = 10

  { // ---- stage qn, kn (token t) ----
    const int ty = t >> 4, tx = t & 15;
    const int pix = bb*HWC + (wy*16+ty)*128 + wx*16 + tx;
    const float* row = qkv + (long)pix*576 + h*32;
    float qv[32], kv[32];
    float sq = 0.f, sk = 0.f;
    #pragma unroll
    for (int d=0; d<32; d+=4){
      float4 a = *(const float4*)(row + d);
      float4 b = *(const float4*)(row + 192 + d);
      qv[d]=a.x; qv[d+1]=a.y; qv[d+2]=a.z; qv[d+3]=a.w;
      kv[d]=b.x; kv[d+1]=b.y; kv[d+2]=b.z; kv[d+3]=b.w;
      sq += a.x*a.x + a.y*a.y + a.z*a.z + a.w*a.w;
      sk += b.x*b.x + b.y*b.y + b.z*b.z + b.w*b.w;
    }
    float qinv = sc / fmaxf(sqrtf(sq), 1e-12f);
    float kinv = 1.0f / fmaxf(sqrtf(sk), 1e-12f);
    union { unsigned short u[32]; uint4 v4[4]; } qp, kp;
    #pragma unroll
    for (int d=0; d<32; d++){ qp.u[d] = f2b(qv[d]*qinv); kp.u[d] = f2b(kv[d]*kinv); }
    #pragma unroll
    for (int o=0;o<4;o++){
      *(uint4*)&qs[t*KSP + o*8] = qp.v4[o];
      *(uint4*)&ks[t*KSP + o*8] = kp.v4[o];
    }
  }
  { // ---- stage v transposed: thread (d, kt) handles 32 keys for dim d ----
    const int d = t & 31, kt = t >> 5;
    union { unsigned short u[32]; uint4 v4[4]; } vp;
    #pragma unroll 4
    for (int i=0;i<32;i++){
      int key = kt*32 + i;
      int pixk = bb*HWC + (wy*16 + (key>>4))*128 + wx*16 + (key&15);
      vp.u[i] = f2b(qkv[(long)pixk*576 + 384 + h*32 + d]);
    }
    #pragma unroll
    for (int o=0;o<4;o++) *(uint4*)&vt[d*VTP + kt*32 + o*8] = vp.v4[o];
  }
  __syncthreads();

  const int wv = t >> 6, lane = t & 63;
  const int l15 = lane & 15, q = lane >> 4;
  short8x qa[4];
  #pragma unroll
  for (int mi=0; mi<4; mi++)
    qa[mi] = *(const short8x*)&qs[(wv*64 + mi*16 + l15)*KSP + q*8];
  __syncthreads();   // qs region now free for ps use

  f32x4 oacc[4][2], lsum[4];
  #pragma unroll
  for (int mi=0;mi<4;mi++){
    oacc[mi][0] = (f32x4){0.f,0.f,0.f,0.f};
    oacc[mi][1] = (f32x4){0.f,0.f,0.f,0.f};
    lsum[mi]    = (f32x4){0.f,0.f,0.f,0.f};
  }
  const float* bias_h = bias + (h << 16);
  unsigned short* myps = ps[wv];

  for (int kt=0; kt<8; kt++){
    const int k0 = kt*32;
    short8x kb0 = *(const short8x*)&ks[(k0 + l15)*KSP + q*8];
    short8x kb1 = *(const short8x*)&ks[(k0 + 16 + l15)*KSP + q*8];
    f32x4 s[4][2];
    #pragma unroll
    for (int mi=0; mi<4; mi++){
      f32x4 z0 = (f32x4){0.f,0.f,0.f,0.f};
      s[mi][0] = __builtin_amdgcn_mfma_f32_16x16x32_bf16(qa[mi], kb0, z0, 0,0,0);
      s[mi][1] = __builtin_amdgcn_mfma_f32_16x16x32_bf16(qa[mi], kb1, z0, 0,0,0);
    }
    // bias + exp + P pack
    #pragma unroll
    for (int mi=0; mi<4; mi++){
      #pragma unroll
      for (int r=0; r<4; r++){
        int rowq = wv*64 + mi*16 + q*4 + r;
        const float* brow = bias_h + rowq*256 + k0;
        float e0 = __expf(fminf(s[mi][0][r] + brow[l15],      30.f));
        float e1 = __expf(fminf(s[mi][1][r] + brow[16 + l15], 30.f));
        lsum[mi][r] += e0 + e1;
        myps[(mi*16 + q*4 + r)*KSP + l15]      = f2b(e0);
        myps[(mi*16 + q*4 + r)*KSP + 16 + l15] = f2b(e1);
      }
    }
    // PV (same-wave LDS RAW: DS ops in order per wave)
    short8x vb0 = *(const short8x*)&vt[(l15)*VTP      + k0 + q*8];
    short8x vb1 = *(const short8x*)&vt[(16 + l15)*VTP + k0 + q*8];
    #pragma unroll
    for (int mi=0; mi<4; mi++){
      short8x pa = *(const short8x*)&myps[(mi*16 + l15)*KSP + q*8];
      oacc[mi][0] = __builtin_amdgcn_mfma_f32_16x16x32_bf16(pa, vb0, oacc[mi][0], 0,0,0);
      oacc[mi][1] = __builtin_amdgcn_mfma_f32_16x16x32_bf16(pa, vb1, oacc[mi][1], 0,0,0);
    }
  }
  // reduce lsum across the 16 lanes of each quad (cols of the key dim)
  #pragma unroll
  for (int mi=0; mi<4; mi++){
    #pragma unroll
    for (int r=0; r<4; r++){
      float v = lsum[mi][r];
      v += __shfl_xor(v, 1);
      v += __shfl_xor(v, 2);
      v += __shfl_xor(v, 4);
      v += __shfl_xor(v, 8);
      lsum[mi][r] = v;
    }
  }
  #pragma unroll
  for (int mi=0; mi<4; mi++){
    #pragma unroll
    for (int r=0; r<4; r++){
      int rowq = wv*64 + mi*16 + q*4 + r;
      int pixo = bb*HWC + (wy*16 + (rowq>>4))*128 + wx*16 + (rowq&15);
      float inv = 1.0f / lsum[mi][r];
      aout[(long)pixo*CCH + h*32 + l15]      = f2b(oacc[mi][0][r]*inv);
      aout[(long)pixo*CCH + h*32 + 16 + l15] = f2b(oacc[mi][1][r]*inv);
    }
  }
}

// ------- proj GEMM via MFMA: aout16 @ WP^T + b -> NCHW f32 (coalesced) ------
__global__ __launch_bounds__(256, 3) void proj_mfma(
    const unsigned short* __restrict__ a16,   // [65536][192] bf16
    const unsigned short* __restrict__ w16,   // [192][192] bf16
    const float* __restrict__ bias,
    float* __restrict__ outp)                 // NCHW f32
{
  __shared__ unsigned short sB[128*LDA];
  const int tid = threadIdx.x;
  const int n0 = blockIdx.x * 128;            // pixel base
  #pragma unroll
  for (int i=0;i<12;i++){
    int idx = tid + i*256;
    int row = idx / 24, oct = idx - row*24;
    uint4 v = *(const uint4*)(a16 + (long)(n0+row)*CCH + oct*8);
    *(uint4*)&sB[row*LDA + oct*8] = v;
  }
  __syncthreads();
  const int wv = tid >> 6, lane = tid & 63;
  const int wm = (wv & 1) * 96;               // co offset
  const int wn = (wv >> 1) * 64;              // pix offset in tile
  const int l15 = lane & 15, q = lane >> 4;
  f32x4 acc[6][4];
  #pragma unroll
  for (int mi=0;mi<6;mi++)
    #pragma unroll
    for (int ni=0;ni<4;ni++) acc[mi][ni] = (f32x4){0.f,0.f,0.f,0.f};
  #pragma unroll
  for (int kk=0; kk<6; kk++){
    const int k0 = kk*32;
    short8x af[6], bf[4];
    #pragma unroll
    for (int mi=0; mi<6; mi++)
      af[mi] = *(const short8x*)(w16 + (long)(wm + mi*16 + l15)*CCH + k0 + q*8);
    #pragma unroll
    for (int ni=0; ni<4; ni++)
      bf[ni] = *(const short8x*)&sB[(wn + ni*16 + l15)*LDA + k0 + q*8];
    #pragma unroll
    for (int mi=0; mi<6; mi++)
      #pragma unroll
      for (int ni=0; ni<4; ni++)
        acc[mi][ni] = __builtin_amdgcn_mfma_f32_16x16x32_bf16(af[mi], bf[ni], acc[mi][ni], 0,0,0);
  }
  #pragma unroll
  for (int mi=0; mi<6; mi++){
    #pragma unroll
    for (int r=0; r<4; r++){
      int co = wm + mi*16 + q*4 + r;
      float bv = bias[co];
      #pragma unroll
      for (int ni=0; ni<4; ni++){
        int pix = n0 + wn + ni*16 + l15;
        int b = pix >> 14, hw = pix & (HWC-1);
        outp[((long)b*CCH + co)*HWC + hw] = acc[mi][ni][r] + bv;
      }
    }
  }
}

// ---------------------------------------------------------------------------
extern "C" void kernel_launch(void* const* d_in, const int* in_sizes, int n_in,
                              void* d_out, int out_size, void* d_ws, size_t ws_size,
                              hipStream_t stream)
{
  const float* x       = (const float*)d_in[0];
  const float* p1_w    = (const float*)d_in[1];
  const float* p1_b    = (const float*)d_in[2];
  const float* pw_w    = (const float*)d_in[3];
  const float* pw_b    = (const float*)d_in[4];
  const float* dw_w    = (const float*)d_in[5];
  const float* dw_b    = (const float*)d_in[6];
  const float* dd_w    = (const float*)d_in[7];
  const float* dd_b    = (const float*)d_in[8];
  const float* p2_w    = (const float*)d_in[9];
  const float* p2_b    = (const float*)d_in[10];
  const float* ln_g    = (const float*)d_in[11];
  const float* ln_b    = (const float*)d_in[12];
  const float* qkv_w   = (const float*)d_in[13];
  const float* q_bias  = (const float*)d_in[14];
  const float* v_bias  = (const float*)d_in[15];
  const float* lscale  = (const float*)d_in[16];
  const float* cpb_w1  = (const float*)d_in[17];
  const float* cpb_b1  = (const float*)d_in[18];
  const float* cpb_w2  = (const float*)d_in[19];
  const float* proj_w  = (const float*)d_in[20];
  const float* proj_b  = (const float*)d_in[21];

  float* ws = (float*)d_ws;
  const long A = 12582912L;           // 4*192*128*128
  float* R0 = ws;                     // y ; later qkv f32 spans R0..R2 (3A)
  float* R1 = ws + A;                 // a / a3
  float* R2 = ws + 2*A;               // dw tmp / y2
  unsigned short* Z16  = (unsigned short*)(ws + 3*A);   // A ushorts
  unsigned short* AO16 = Z16;                           // attn out reuses z16
  unsigned short* WQ   = (unsigned short*)(ws + 3*A + A/2);        // 110592
  unsigned short* WP   = WQ + 110592;                               // 36864
  float* RB = ws + 4*A;               // bias table (6*256*256), shifted by -16
  float* T6 = RB + 393216;            // cpb mlp out (961*6)

  // weight casts + CPB bias table (independent of main chain)
  cast_w_kernel<<<432, 256, 0, stream>>>(qkv_w, proj_w, WQ, WP);
  cpb_mlp_kernel<<<961, 128, 0, stream>>>(cpb_w1, cpb_b1, cpb_w2, T6);
  cpb_expand_kernel<<<1536, 256, 0, stream>>>(T6, RB);

  // VAB conv block (fp32 scalar path, unchanged)
  pw_kernel<0><<<1024, 256, 0, stream>>>(x, nullptr, nullptr, p1_w, p1_b, R0);
  pw_kernel<1><<<1024, 256, 0, stream>>>(nullptr, R0, nullptr, pw_w, pw_b, R1);
  dw_kernel<<<49152, 256, 0, stream>>>(R1, dw_w, dw_b, R2, 2, 1);
  dw_kernel<<<49152, 256, 0, stream>>>(R2, dd_w, dd_b, R1, 6, 3);
  pw_kernel<2><<<1024, 256, 0, stream>>>(x, R0, R1, p2_w, p2_b, R2);

  // LN -> z bf16 (NHWC row-major, K-contiguous)
  ln_kernel<<<1024, 256, 0, stream>>>(R2, ln_g, ln_b, Z16);

  // qkv GEMM on MFMA
  qkv_mfma<<<dim3(512, 3), 256, 0, stream>>>(Z16, WQ, q_bias, v_bias, R0);

  // window attention on MFMA (z16 dead -> reuse as AO16)
  attn_mfma<<<dim3(256, 6), 256, 0, stream>>>(R0, RB, lscale, AO16);

  // projection on MFMA + window-reverse -> f32 NCHW
  proj_mfma<<<512, 256, 0, stream>>>(AO16, WP, proj_b, (float*)d_out);
}

// Round 5
// 676.062 us; speedup vs baseline: 2.7344x; 1.4211x over previous
//
#include <hip/hip_runtime.h>
#include <hip/hip_bf16.h>
#include <math.h>

// Shapes: B=4, C=192, H=W=128, window 16 -> 256 windows of 256 tokens, 6 heads x 32
#define HWC 16384   // 128*128
#define CCH 192
#define LDA 200     // bf16 elems per LDS row (192 + 8 pad; 400 B, 16B-aligned rows)

typedef __attribute__((ext_vector_type(8))) short short8x;
typedef __attribute__((ext_vector_type(4))) float f32x4;

__device__ __forceinline__ unsigned short f2b(float f){
  union { float f; unsigned int i; } x; x.f = f;
  unsigned int r = x.i + 0x7FFFu + ((x.i >> 16) & 1u);   // RNE
  return (unsigned short)(r >> 16);
}
__device__ __forceinline__ float gelu_exact(float v){
  return 0.5f * v * (1.0f + erff(v * 0.70710678118654752440f));
}

// ---------------- weight cast fp32 -> bf16 (qkv_w 110592, proj_w 36864) -----
__global__ __launch_bounds__(256) void cast_w_kernel(
    const float* __restrict__ qkvw, const float* __restrict__ projw,
    unsigned short* __restrict__ wq, unsigned short* __restrict__ wp)
{
  int i = blockIdx.x*256 + threadIdx.x;
  if (i < 110592) wq[i] = f2b(qkvw[i]);
  if (i < 36864)  wp[i] = f2b(projw[i]);
}

// ---------------- pointwise 1x1 conv (NCHW), register-tiled GEMM -------------
template<int MODE>
__global__ __launch_bounds__(256) void pw_kernel(
    const float* __restrict__ xres,
    const float* __restrict__ inA,
    const float* __restrict__ inB,
    const float* __restrict__ w,     // [co][ci]
    const float* __restrict__ bias,  // [co]
    float* __restrict__ out)
{
  __shared__ float xs[96*68];
  __shared__ float wt[96*68];
  const int tid = threadIdx.x;
  const int pix0 = blockIdx.x * 64;
  const int bb = pix0 >> 14;
  const int hw0 = pix0 & (HWC-1);
  const long base = (long)bb * CCH * HWC + hw0;
  const int tp = tid & 15, tc = tid >> 4;

  float acc[3][4][4];
  #pragma unroll
  for (int coc=0; coc<3; coc++){
    #pragma unroll
    for (int u=0; u<4; u++){
      float bv = bias[coc*64 + tc*4 + u];
      #pragma unroll
      for (int v=0; v<4; v++) acc[coc][u][v] = bv;
    }
  }
  #pragma unroll
  for (int cic=0; cic<2; cic++){
    #pragma unroll
    for (int coc=0; coc<3; coc++){
      __syncthreads();
      if (coc == 0){
        #pragma unroll
        for (int i=0;i<24;i++){
          int idx = tid + i*256;
          int cil = idx >> 6, pix = idx & 63;
          long g = base + (long)(cic*96 + cil)*HWC + pix;
          float v;
          if (MODE==0)      v = xres[g];
          else if (MODE==1) v = inA[g];
          else              v = inA[g]*inB[g];
          xs[cil*68 + pix] = v;
        }
      }
      #pragma unroll
      for (int i=0;i<24;i++){
        int idx = tid + i*256;
        int cc2 = idx / 96, cil = idx - cc2*96;
        wt[cil*68 + cc2] = w[(coc*64+cc2)*CCH + cic*96 + cil];
      }
      __syncthreads();
      #pragma unroll 2
      for (int cil=0; cil<96; cil++){
        float4 xv = *(const float4*)&xs[cil*68 + tp*4];
        float4 wv = *(const float4*)&wt[cil*68 + tc*4];
        float xa[4] = {xv.x, xv.y, xv.z, xv.w};
        float wa[4] = {wv.x, wv.y, wv.z, wv.w};
        #pragma unroll
        for (int u=0;u<4;u++)
          #pragma unroll
          for (int v=0;v<4;v++)
            acc[coc][u][v] = fmaf(wa[u], xa[v], acc[coc][u][v]);
      }
    }
  }
  #pragma unroll
  for (int coc=0; coc<3; coc++){
    #pragma unroll
    for (int u=0; u<4; u++){
      int co = coc*64 + tc*4 + u;
      long g = base + (long)co*HWC + tp*4;
      float t0 = acc[coc][u][0], t1 = acc[coc][u][1];
      float t2 = acc[coc][u][2], t3 = acc[coc][u][3];
      if (MODE==0){ t0=gelu_exact(t0); t1=gelu_exact(t1); t2=gelu_exact(t2); t3=gelu_exact(t3); }
      if (MODE==2){
        float4 rv = *(const float4*)&xres[g];
        t0 += rv.x; t1 += rv.y; t2 += rv.z; t3 += rv.w;
      }
      float4 r; r.x=t0; r.y=t1; r.z=t2; r.w=t3;
      *(float4*)&out[g] = r;
    }
  }
}

// -------- depthwise 5x5 conv, quad-output vectorized, XCD-swizzled ----------
// Each thread computes 4 horizontal outputs; rows loaded as aligned float4s.
// Invalid taps select 0 (fma(w,0,acc)==acc -> bit-identical to scalar version).
template<int PAD, int DIL>
__global__ __launch_bounds__(256) void dw4_kernel(
    const float* __restrict__ in, const float* __restrict__ w,
    const float* __restrict__ bias, float* __restrict__ out)
{
  // XCD swizzle: dispatch is round-robin over 8 XCDs; give each XCD a
  // contiguous span of planes so the vertical halo stays L2-local.
  const int g = blockIdx.x;                 // grid = 12288
  const int wid = (g & 7) * 1536 + (g >> 3);
  const int qid = wid * 256 + threadIdx.x;  // quad id
  const int x4  = (qid & 31) * 4;           // output col base
  const int row = (qid >> 5) & 127;
  const int bc  = qid >> 12;                // b*192 + c
  const int c   = bc % 192;
  const float* ip = in + (long)bc * HWC;

  constexpr int NQ = (DIL==1) ? 3 : 5;      // float4 loads per row
  constexpr int Q0 = (DIL==1) ? 1 : 2;      // quads before x4

  float bv = bias[c];
  float acc[4] = {bv, bv, bv, bv};

  #pragma unroll
  for (int kh=0; kh<5; kh++){
    int ih = row + kh*DIL - PAD;
    if ((unsigned)ih < 128u){
      const float* irow = ip + ih*128 + x4 - Q0*4;
      float rv[NQ*4];
      #pragma unroll
      for (int qq=0; qq<NQ; qq++){
        float4 v = *(const float4*)(irow + qq*4);
        rv[qq*4+0]=v.x; rv[qq*4+1]=v.y; rv[qq*4+2]=v.z; rv[qq*4+3]=v.w;
      }
      #pragma unroll
      for (int kw=0; kw<5; kw++){
        float wv = w[c*25 + kh*5 + kw];
        const int off = kw*DIL - PAD;
        #pragma unroll
        for (int j=0;j<4;j++){
          int xx = x4 + off + j;
          float v = ((unsigned)xx < 128u) ? rv[Q0*4 + off + j] : 0.0f;
          acc[j] = fmaf(wv, v, acc[j]);
        }
      }
    }
  }
  float4 r; r.x=acc[0]; r.y=acc[1]; r.z=acc[2]; r.w=acc[3];
  *(float4*)&out[(long)bc*HWC + row*128 + x4] = r;
}

// -------- LayerNorm over C, NCHW f32 -> NHWC *bf16* (z16, K-contiguous) -----
__global__ __launch_bounds__(256) void ln_kernel(
    const float* __restrict__ in, const float* __restrict__ gam,
    const float* __restrict__ bet, unsigned short* __restrict__ z16)
{
  __shared__ float xs[CCH*68];
  __shared__ float ps[4*64], ps2[4*64], smu[64], srs[64];
  const int tid = threadIdx.x;
  const int pix0 = blockIdx.x * 64;
  const int bb = pix0 >> 14;
  const int hw0 = pix0 & (HWC-1);
  const long base = (long)bb * CCH * HWC + hw0;
  #pragma unroll 8
  for (int i=0;i<48;i++){
    int idx = tid + i*256;
    int ci = idx >> 6, pix = idx & 63;
    xs[ci*68 + pix] = in[base + (long)ci*HWC + pix];
  }
  __syncthreads();
  {
    int pix = tid & 63, g = tid >> 6;
    float s=0.f, s2=0.f;
    for (int ci=g*48; ci<g*48+48; ci++){
      float v = xs[ci*68 + pix]; s += v; s2 = fmaf(v, v, s2);
    }
    ps[g*64+pix] = s; ps2[g*64+pix] = s2;
  }
  __syncthreads();
  if (tid < 64){
    float s  = ps[tid]  + ps[64+tid]  + ps[128+tid]  + ps[192+tid];
    float s2 = ps2[tid] + ps2[64+tid] + ps2[128+tid] + ps2[192+tid];
    float mu = s * (1.0f/192.0f);
    float var = s2 * (1.0f/192.0f) - mu*mu;
    smu[tid] = mu;
    srs[tid] = rsqrtf(var + 1e-5f);
  }
  __syncthreads();
  #pragma unroll 8
  for (int i=0;i<48;i++){
    int idx = tid + i*256;
    int pix = idx / 192, ci = idx - pix*192;
    float v = (xs[ci*68 + pix] - smu[pix]) * srs[pix] * gam[ci] + bet[ci];
    z16[(long)(pix0 + pix)*CCH + ci] = f2b(v);
  }
}

// ---------------- qkv GEMM via MFMA: z16[65536][192] @ WQ^T -> qkv f32 ------
__global__ __launch_bounds__(256, 3) void qkv_mfma(
    const unsigned short* __restrict__ z16,   // [65536][192] bf16
    const unsigned short* __restrict__ w16,   // [576][192] bf16
    const float* __restrict__ qb, const float* __restrict__ vb,
    float* __restrict__ qkv)                  // [65536][576] f32
{
  __shared__ unsigned short sA[128*LDA];      // 51200 B
  const int tid = threadIdx.x;
  const int m0 = blockIdx.x * 128;            // pixel base
  const int s  = blockIdx.y;                  // 0=q,1=k,2=v
  #pragma unroll
  for (int i=0;i<12;i++){
    int idx = tid + i*256;
    int row = idx / 24, oct = idx - row*24;
    uint4 v = *(const uint4*)(z16 + (long)(m0+row)*CCH + oct*8);
    *(uint4*)&sA[row*LDA + oct*8] = v;
  }
  __syncthreads();
  const int wv = tid >> 6, lane = tid & 63;
  const int wm = (wv & 1) * 64;               // pix offset in tile
  const int wn = (wv >> 1) * 96;              // co offset in slice
  const int l15 = lane & 15, q = lane >> 4;
  const unsigned short* wbase = w16 + (long)(s*192)*CCH;
  f32x4 acc[4][6];
  #pragma unroll
  for (int mi=0;mi<4;mi++)
    #pragma unroll
    for (int ni=0;ni<6;ni++) acc[mi][ni] = (f32x4){0.f,0.f,0.f,0.f};
  #pragma unroll
  for (int kk=0; kk<6; kk++){
    const int k0 = kk*32;
    short8x af[4], bf[6];
    #pragma unroll
    for (int mi=0; mi<4; mi++)
      af[mi] = *(const short8x*)&sA[(wm + mi*16 + l15)*LDA + k0 + q*8];
    #pragma unroll
    for (int ni=0; ni<6; ni++)
      bf[ni] = *(const short8x*)(wbase + (long)(wn + ni*16 + l15)*CCH + k0 + q*8);
    #pragma unroll
    for (int mi=0; mi<4; mi++)
      #pragma unroll
      for (int ni=0; ni<6; ni++)
        acc[mi][ni] = __builtin_amdgcn_mfma_f32_16x16x32_bf16(af[mi], bf[ni], acc[mi][ni], 0,0,0);
  }
  #pragma unroll
  for (int ni=0; ni<6; ni++){
    int co = wn + ni*16 + l15;                // 0..191 within slice
    float bv = (s==0) ? qb[co] : ((s==2) ? vb[co] : 0.0f);
    #pragma unroll
    for (int mi=0; mi<4; mi++){
      #pragma unroll
      for (int r=0; r<4; r++){
        int pix = m0 + wm + mi*16 + q*4 + r;
        qkv[(long)pix*576 + s*192 + co] = acc[mi][ni][r] + bv;
      }
    }
  }
}

// ---------------- CPB MLP: table(961,2) -> (961,6) --------------------------
__device__ __forceinline__ float cpb_coord(int a){
  float r = ((float)a - 15.0f) * (8.0f/15.0f);
  float t = log2f(fabsf(r) + 1.0f) * (1.0f/3.0f);
  return (r < 0.f) ? -t : t;
}
__global__ __launch_bounds__(128) void cpb_mlp_kernel(
    const float* __restrict__ w1, const float* __restrict__ b1,
    const float* __restrict__ w2, float* __restrict__ tbl6)
{
  int e = blockIdx.x;
  int a = e / 31, bb = e - a*31;
  float t0 = cpb_coord(a), t1 = cpb_coord(bb);
  float p[6] = {0,0,0,0,0,0};
  for (int hh = threadIdx.x; hh < 512; hh += 128){
    float hid = t0*w1[hh*2] + t1*w1[hh*2+1] + b1[hh];
    hid = fmaxf(hid, 0.0f);
    #pragma unroll
    for (int hd=0; hd<6; hd++) p[hd] = fmaf(hid, w2[hd*512 + hh], p[hd]);
  }
  __shared__ float red[6][128];
  #pragma unroll
  for (int hd=0; hd<6; hd++) red[hd][threadIdx.x] = p[hd];
  __syncthreads();
  if (threadIdx.x < 6){
    float sum = 0.f;
    for (int i=0;i<128;i++) sum += red[threadIdx.x][i];
    tbl6[e*6 + threadIdx.x] = sum;
  }
}
// expand to bias[h][i][j] = 16*sigmoid(tbl6[relidx(i,j)][h]) - 16  (shift folded
// in so attention exponents are <= 10: softmax is shift-invariant)
__global__ __launch_bounds__(256) void cpb_expand_kernel(
    const float* __restrict__ tbl6, float* __restrict__ bias)
{
  int idx = blockIdx.x*256 + threadIdx.x;      // < 6*256*256
  int h = idx >> 16;
  int rem = idx & 65535;
  int i = rem >> 8, j = rem & 255;
  int dy = (i>>4) - (j>>4) + 15;
  int dx = (i&15) - (j&15) + 15;
  float v = tbl6[(dy*31+dx)*6 + h];
  bias[idx] = 16.0f / (1.0f + __expf(-v)) - 16.0f;
}

// ------------- windowed cosine attention via MFMA, block=(win, head) --------
#define KSP 40    // ks/qs/ps row stride (shorts): 80 B, 16B-aligned, 2-way banks
#define VTP 264   // vt row stride (shorts): 528 B, 16B-aligned, 2-way banks
__global__ __launch_bounds__(256) void attn_mfma(
    const float* __restrict__ qkv, const float* __restrict__ bias,
    const float* __restrict__ ls, unsigned short* __restrict__ aout)
{
  __shared__ unsigned short ks[256*KSP];      // 20480 B  kn bf16 [key][d]
  __shared__ unsigned short vt[32*VTP];       // 16896 B  v bf16 [d][key]
  __shared__ unsigned short ps[4][64*KSP];    // 20480 B  per-wave P / (init: qs)
  unsigned short* qs = &ps[0][0];             // 256*40 shorts = 10240 fits 4*2560

  const int win = blockIdx.x, h = blockIdx.y;
  const int t = threadIdx.x;
  const int bb = win >> 6;
  const int wy = (win >> 3) & 7, wx = win & 7;
  const float sc = __expf(fminf(ls[h], 4.60517018598809136804f));  // = 10

  { // ---- stage qn, kn (token t) ----
    const int ty = t >> 4, tx = t & 15;
    const int pix = bb*HWC + (wy*16+ty)*128 + wx*16 + tx;
    const float* row = qkv + (long)pix*576 + h*32;
    float qv[32], kv[32];
    float sq = 0.f, sk = 0.f;
    #pragma unroll
    for (int d=0; d<32; d+=4){
      float4 a = *(const float4*)(row + d);
      float4 b = *(const float4*)(row + 192 + d);
      qv[d]=a.x; qv[d+1]=a.y; qv[d+2]=a.z; qv[d+3]=a.w;
      kv[d]=b.x; kv[d+1]=b.y; kv[d+2]=b.z; kv[d+3]=b.w;
      sq += a.x*a.x + a.y*a.y + a.z*a.z + a.w*a.w;
      sk += b.x*b.x + b.y*b.y + b.z*b.z + b.w*b.w;
    }
    float qinv = sc / fmaxf(sqrtf(sq), 1e-12f);
    float kinv = 1.0f / fmaxf(sqrtf(sk), 1e-12f);
    union { unsigned short u[32]; uint4 v4[4]; } qp, kp;
    #pragma unroll
    for (int d=0; d<32; d++){ qp.u[d] = f2b(qv[d]*qinv); kp.u[d] = f2b(kv[d]*kinv); }
    #pragma unroll
    for (int o=0;o<4;o++){
      *(uint4*)&qs[t*KSP + o*8] = qp.v4[o];
      *(uint4*)&ks[t*KSP + o*8] = kp.v4[o];
    }
  }
  { // ---- stage v transposed: thread (d, kt) handles 32 keys for dim d ----
    const int d = t & 31, kt = t >> 5;
    union { unsigned short u[32]; uint4 v4[4]; } vp;
    #pragma unroll 4
    for (int i=0;i<32;i++){
      int key = kt*32 + i;
      int pixk = bb*HWC + (wy*16 + (key>>4))*128 + wx*16 + (key&15);
      vp.u[i] = f2b(qkv[(long)pixk*576 + 384 + h*32 + d]);
    }
    #pragma unroll
    for (int o=0;o<4;o++) *(uint4*)&vt[d*VTP + kt*32 + o*8] = vp.v4[o];
  }
  __syncthreads();

  const int wv = t >> 6, lane = t & 63;
  const int l15 = lane & 15, q = lane >> 4;
  short8x qa[4];
  #pragma unroll
  for (int mi=0; mi<4; mi++)
    qa[mi] = *(const short8x*)&qs[(wv*64 + mi*16 + l15)*KSP + q*8];
  __syncthreads();   // qs region now free for ps use

  f32x4 oacc[4][2], lsum[4];
  #pragma unroll
  for (int mi=0;mi<4;mi++){
    oacc[mi][0] = (f32x4){0.f,0.f,0.f,0.f};
    oacc[mi][1] = (f32x4){0.f,0.f,0.f,0.f};
    lsum[mi]    = (f32x4){0.f,0.f,0.f,0.f};
  }
  const float* bias_h = bias + (h << 16);
  unsigned short* myps = ps[wv];

  for (int kt=0; kt<8; kt++){
    const int k0 = kt*32;
    short8x kb0 = *(const short8x*)&ks[(k0 + l15)*KSP + q*8];
    short8x kb1 = *(const short8x*)&ks[(k0 + 16 + l15)*KSP + q*8];
    f32x4 s[4][2];
    #pragma unroll
    for (int mi=0; mi<4; mi++){
      f32x4 z0 = (f32x4){0.f,0.f,0.f,0.f};
      s[mi][0] = __builtin_amdgcn_mfma_f32_16x16x32_bf16(qa[mi], kb0, z0, 0,0,0);
      s[mi][1] = __builtin_amdgcn_mfma_f32_16x16x32_bf16(qa[mi], kb1, z0, 0,0,0);
    }
    // bias + exp + P pack
    #pragma unroll
    for (int mi=0; mi<4; mi++){
      #pragma unroll
      for (int r=0; r<4; r++){
        int rowq = wv*64 + mi*16 + q*4 + r;
        const float* brow = bias_h + rowq*256 + k0;
        float e0 = __expf(fminf(s[mi][0][r] + brow[l15],      30.f));
        float e1 = __expf(fminf(s[mi][1][r] + brow[16 + l15], 30.f));
        lsum[mi][r] += e0 + e1;
        myps[(mi*16 + q*4 + r)*KSP + l15]      = f2b(e0);
        myps[(mi*16 + q*4 + r)*KSP + 16 + l15] = f2b(e1);
      }
    }
    // PV (same-wave LDS RAW: DS ops in order per wave)
    short8x vb0 = *(const short8x*)&vt[(l15)*VTP      + k0 + q*8];
    short8x vb1 = *(const short8x*)&vt[(16 + l15)*VTP + k0 + q*8];
    #pragma unroll
    for (int mi=0; mi<4; mi++){
      short8x pa = *(const short8x*)&myps[(mi*16 + l15)*KSP + q*8];
      oacc[mi][0] = __builtin_amdgcn_mfma_f32_16x16x32_bf16(pa, vb0, oacc[mi][0], 0,0,0);
      oacc[mi][1] = __builtin_amdgcn_mfma_f32_16x16x32_bf16(pa, vb1, oacc[mi][1], 0,0,0);
    }
  }
  // reduce lsum across the 16 lanes of each quad (cols of the key dim)
  #pragma unroll
  for (int mi=0; mi<4; mi++){
    #pragma unroll
    for (int r=0; r<4; r++){
      float v = lsum[mi][r];
      v += __shfl_xor(v, 1);
      v += __shfl_xor(v, 2);
      v += __shfl_xor(v, 4);
      v += __shfl_xor(v, 8);
      lsum[mi][r] = v;
    }
  }
  #pragma unroll
  for (int mi=0; mi<4; mi++){
    #pragma unroll
    for (int r=0; r<4; r++){
      int rowq = wv*64 + mi*16 + q*4 + r;
      int pixo = bb*HWC + (wy*16 + (rowq>>4))*128 + wx*16 + (rowq&15);
      float inv = 1.0f / lsum[mi][r];
      aout[(long)pixo*CCH + h*32 + l15]      = f2b(oacc[mi][0][r]*inv);
      aout[(long)pixo*CCH + h*32 + 16 + l15] = f2b(oacc[mi][1][r]*inv);
    }
  }
}

// ------- proj GEMM via MFMA: aout16 @ WP^T + b -> NCHW f32 (coalesced) ------
__global__ __launch_bounds__(256, 3) void proj_mfma(
    const unsigned short* __restrict__ a16,   // [65536][192] bf16
    const unsigned short* __restrict__ w16,   // [192][192] bf16
    const float* __restrict__ bias,
    float* __restrict__ outp)                 // NCHW f32
{
  __shared__ unsigned short sB[128*LDA];
  const int tid = threadIdx.x;
  const int n0 = blockIdx.x * 128;            // pixel base
  #pragma unroll
  for (int i=0;i<12;i++){
    int idx = tid + i*256;
    int row = idx / 24, oct = idx - row*24;
    uint4 v = *(const uint4*)(a16 + (long)(n0+row)*CCH + oct*8);
    *(uint4*)&sB[row*LDA + oct*8] = v;
  }
  __syncthreads();
  const int wv = tid >> 6, lane = tid & 63;
  const int wm = (wv & 1) * 96;               // co offset
  const int wn = (wv >> 1) * 64;              // pix offset in tile
  const int l15 = lane & 15, q = lane >> 4;
  f32x4 acc[6][4];
  #pragma unroll
  for (int mi=0;mi<6;mi++)
    #pragma unroll
    for (int ni=0;ni<4;ni++) acc[mi][ni] = (f32x4){0.f,0.f,0.f,0.f};
  #pragma unroll
  for (int kk=0; kk<6; kk++){
    const int k0 = kk*32;
    short8x af[6], bf[4];
    #pragma unroll
    for (int mi=0; mi<6; mi++)
      af[mi] = *(const short8x*)(w16 + (long)(wm + mi*16 + l15)*CCH + k0 + q*8);
    #pragma unroll
    for (int ni=0; ni<4; ni++)
      bf[ni] = *(const short8x*)&sB[(wn + ni*16 + l15)*LDA + k0 + q*8];
    #pragma unroll
    for (int mi=0; mi<6; mi++)
      #pragma unroll
      for (int ni=0; ni<4; ni++)
        acc[mi][ni] = __builtin_amdgcn_mfma_f32_16x16x32_bf16(af[mi], bf[ni], acc[mi][ni], 0,0,0);
  }
  #pragma unroll
  for (int mi=0; mi<6; mi++){
    #pragma unroll
    for (int r=0; r<4; r++){
      int co = wm + mi*16 + q*4 + r;
      float bv = bias[co];
      #pragma unroll
      for (int ni=0; ni<4; ni++){
        int pix = n0 + wn + ni*16 + l15;
        int b = pix >> 14, hw = pix & (HWC-1);
        outp[((long)b*CCH + co)*HWC + hw] = acc[mi][ni][r] + bv;
      }
    }
  }
}

// ---------------------------------------------------------------------------
extern "C" void kernel_launch(void* const* d_in, const int* in_sizes, int n_in,
                              void* d_out, int out_size, void* d_ws, size_t ws_size,
                              hipStream_t stream)
{
  const float* x       = (const float*)d_in[0];
  const float* p1_w    = (const float*)d_in[1];
  const float* p1_b    = (const float*)d_in[2];
  const float* pw_w    = (const float*)d_in[3];
  const float* pw_b    = (const float*)d_in[4];
  const float* dw_w    = (const float*)d_in[5];
  const float* dw_b    = (const float*)d_in[6];
  const float* dd_w    = (const float*)d_in[7];
  const float* dd_b    = (const float*)d_in[8];
  const float* p2_w    = (const float*)d_in[9];
  const float* p2_b    = (const float*)d_in[10];
  const float* ln_g    = (const float*)d_in[11];
  const float* ln_b    = (const float*)d_in[12];
  const float* qkv_w   = (const float*)d_in[13];
  const float* q_bias  = (const float*)d_in[14];
  const float* v_bias  = (const float*)d_in[15];
  const float* lscale  = (const float*)d_in[16];
  const float* cpb_w1  = (const float*)d_in[17];
  const float* cpb_b1  = (const float*)d_in[18];
  const float* cpb_w2  = (const float*)d_in[19];
  const float* proj_w  = (const float*)d_in[20];
  const float* proj_b  = (const float*)d_in[21];

  float* ws = (float*)d_ws;
  const long A = 12582912L;           // 4*192*128*128
  float* R0 = ws;                     // y ; later qkv f32 spans R0..R2 (3A)
  float* R1 = ws + A;                 // a / a3
  float* R2 = ws + 2*A;               // dw tmp / y2
  unsigned short* Z16  = (unsigned short*)(ws + 3*A);   // A ushorts
  unsigned short* AO16 = Z16;                           // attn out reuses z16
  unsigned short* WQ   = (unsigned short*)(ws + 3*A + A/2);        // 110592
  unsigned short* WP   = WQ + 110592;                               // 36864
  float* RB = ws + 4*A;               // bias table (6*256*256), shifted by -16
  float* T6 = RB + 393216;            // cpb mlp out (961*6)

  // weight casts + CPB bias table (independent of main chain)
  cast_w_kernel<<<432, 256, 0, stream>>>(qkv_w, proj_w, WQ, WP);
  cpb_mlp_kernel<<<961, 128, 0, stream>>>(cpb_w1, cpb_b1, cpb_w2, T6);
  cpb_expand_kernel<<<1536, 256, 0, stream>>>(T6, RB);

  // VAB conv block
  pw_kernel<0><<<1024, 256, 0, stream>>>(x, nullptr, nullptr, p1_w, p1_b, R0);
  pw_kernel<1><<<1024, 256, 0, stream>>>(nullptr, R0, nullptr, pw_w, pw_b, R1);
  dw4_kernel<2,1><<<12288, 256, 0, stream>>>(R1, dw_w, dw_b, R2);
  dw4_kernel<6,3><<<12288, 256, 0, stream>>>(R2, dd_w, dd_b, R1);
  pw_kernel<2><<<1024, 256, 0, stream>>>(x, R0, R1, p2_w, p2_b, R2);

  // LN -> z bf16 (NHWC row-major, K-contiguous)
  ln_kernel<<<1024, 256, 0, stream>>>(R2, ln_g, ln_b, Z16);

  // qkv GEMM on MFMA
  qkv_mfma<<<dim3(512, 3), 256, 0, stream>>>(Z16, WQ, q_bias, v_bias, R0);

  // window attention on MFMA (z16 dead -> reuse as AO16)
  attn_mfma<<<dim3(256, 6), 256, 0, stream>>>(R0, RB, lscale, AO16);

  // projection on MFMA + window-reverse -> f32 NCHW
  proj_mfma<<<512, 256, 0, stream>>>(AO16, WP, proj_b, (float*)d_out);
}

// Round 6
// 529.500 us; speedup vs baseline: 3.4913x; 1.2768x over previous
//
#include <hip/hip_runtime.h>
#include <hip/hip_bf16.h>
#include <math.h>

// Shapes: B=4, C=192, H=W=128, window 16 -> 256 windows of 256 tokens, 6 heads x 32
#define HWC 16384   // 128*128
#define CCH 192
#define LDA 200     // bf16 elems per LDS row (192 + 8 pad; 400 B, 16B-aligned rows)

typedef __attribute__((ext_vector_type(8))) short short8x;
typedef __attribute__((ext_vector_type(4))) float f32x4;

__device__ __forceinline__ float b2f(unsigned int u){
  union { unsigned int i; float f; } x; x.i = (u & 0xffffu) << 16; return x.f;
}
__device__ __forceinline__ unsigned short f2b(float f){
  union { float f; unsigned int i; } x; x.f = f;
  unsigned int r = x.i + 0x7FFFu + ((x.i >> 16) & 1u);   // RNE
  return (unsigned short)(r >> 16);
}
__device__ __forceinline__ float gelu_exact(float v){
  return 0.5f * v * (1.0f + erff(v * 0.70710678118654752440f));
}

// ------- weight prep: bf16 casts + depthwise-weight transpose [25][192] -----
__global__ __launch_bounds__(256) void cast_w_kernel(
    const float* __restrict__ qkvw, const float* __restrict__ projw,
    const float* __restrict__ p1w,  const float* __restrict__ pww,
    const float* __restrict__ p2w,  const float* __restrict__ dww,
    const float* __restrict__ ddw,
    unsigned short* __restrict__ wq,  unsigned short* __restrict__ wprj,
    unsigned short* __restrict__ wp1, unsigned short* __restrict__ wpa,
    unsigned short* __restrict__ wp2, float* __restrict__ dwt,
    float* __restrict__ ddt)
{
  int i = blockIdx.x*256 + threadIdx.x;
  if (i < 110592) wq[i] = f2b(qkvw[i]);
  if (i < 36864){
    wprj[i] = f2b(projw[i]);
    wp1[i]  = f2b(p1w[i]);
    wpa[i]  = f2b(pww[i]);
    wp2[i]  = f2b(p2w[i]);
  }
  if (i < 4800){
    int t = i / 192, c = i - t*192;
    dwt[i] = dww[c*25 + t];
    ddt[i] = ddw[c*25 + t];
  }
}

// ------- transpose x: NCHW f32 -> NHWC f32 (residual) + NHWC bf16 -----------
__global__ __launch_bounds__(256) void tx_kernel(
    const float* __restrict__ in, float* __restrict__ xt32,
    unsigned short* __restrict__ x16)
{
  __shared__ float xs[CCH*68];
  const int tid = threadIdx.x;
  const int pix0 = blockIdx.x * 64;
  const int bb = pix0 >> 14;
  const int hw0 = pix0 & (HWC-1);
  const long base = (long)bb * CCH * HWC + hw0;
  #pragma unroll 8
  for (int i=0;i<48;i++){
    int idx = tid + i*256;
    int ci = idx >> 6, pix = idx & 63;
    xs[ci*68 + pix] = in[base + (long)ci*HWC + pix];
  }
  __syncthreads();
  #pragma unroll 8
  for (int i=0;i<48;i++){
    int idx = tid + i*256;
    int pix = idx / 192, ci = idx - pix*192;
    float v = xs[ci*68 + pix];
    long g = (long)(pix0 + pix)*CCH + ci;
    xt32[g] = v;
    x16[g]  = f2b(v);
  }
}

// ------- pointwise 1x1 conv via MFMA, NHWC bf16 ----------------------------
// MODE 0: out = gelu(in0 @ W^T + b)            -> bf16
// MODE 1: out = in0 @ W^T + b                  -> bf16
// MODE 2: y2 = (in0*in1) @ W^T + b + xres; LN over C -> z bf16 (fused)
template<int MODE>
__global__ __launch_bounds__(256, 3) void pw_mfma(
    const unsigned short* __restrict__ in0,   // [65536][192] bf16
    const unsigned short* __restrict__ in1,   // [65536][192] bf16 (MODE2)
    const unsigned short* __restrict__ w16,   // [192][192] bf16
    const float* __restrict__ bias,
    const float* __restrict__ xres,           // [65536][192] f32 (MODE2)
    const float* __restrict__ gam, const float* __restrict__ bet,
    unsigned short* __restrict__ out16)
{
  __shared__ unsigned short sA[128*LDA];      // 51200 B
  __shared__ float reds[128*2], reds2[128*2]; // LN cross-wave partials
  const int tid = threadIdx.x;
  const int m0 = blockIdx.x * 128;
  // stage A (product for MODE2)
  #pragma unroll
  for (int i=0;i<12;i++){
    int idx = tid + i*256;
    int row = idx / 24, oct = idx - row*24;
    long g = (long)(m0+row)*CCH + oct*8;
    uint4 vy = *(const uint4*)(in0 + g);
    if (MODE == 2){
      uint4 va = *(const uint4*)(in1 + g);
      unsigned int yy[4] = {vy.x, vy.y, vy.z, vy.w};
      unsigned int aa[4] = {va.x, va.y, va.z, va.w};
      unsigned int rr[4];
      #pragma unroll
      for (int wq2=0; wq2<4; wq2++){
        float lo = b2f(yy[wq2]) * b2f(aa[wq2]);
        float hi = b2f(yy[wq2] >> 16) * b2f(aa[wq2] >> 16);
        rr[wq2] = (unsigned int)f2b(lo) | ((unsigned int)f2b(hi) << 16);
      }
      uint4 vp; vp.x=rr[0]; vp.y=rr[1]; vp.z=rr[2]; vp.w=rr[3];
      *(uint4*)&sA[row*LDA + oct*8] = vp;
    } else {
      *(uint4*)&sA[row*LDA + oct*8] = vy;
    }
  }
  __syncthreads();
  const int wv = tid >> 6, lane = tid & 63;
  const int wm = (wv & 1) * 64;               // pix offset in tile
  const int wn = (wv >> 1) * 96;              // co offset
  const int l15 = lane & 15, q = lane >> 4;
  f32x4 acc[4][6];
  #pragma unroll
  for (int mi=0;mi<4;mi++)
    #pragma unroll
    for (int ni=0;ni<6;ni++) acc[mi][ni] = (f32x4){0.f,0.f,0.f,0.f};
  #pragma unroll
  for (int kk=0; kk<6; kk++){
    const int k0 = kk*32;
    short8x af[4], bf[6];
    #pragma unroll
    for (int mi=0; mi<4; mi++)
      af[mi] = *(const short8x*)&sA[(wm + mi*16 + l15)*LDA + k0 + q*8];
    #pragma unroll
    for (int ni=0; ni<6; ni++)
      bf[ni] = *(const short8x*)(w16 + (long)(wn + ni*16 + l15)*CCH + k0 + q*8);
    #pragma unroll
    for (int mi=0; mi<4; mi++)
      #pragma unroll
      for (int ni=0; ni<6; ni++)
        acc[mi][ni] = __builtin_amdgcn_mfma_f32_16x16x32_bf16(af[mi], bf[ni], acc[mi][ni], 0,0,0);
  }
  float bv[6];
  #pragma unroll
  for (int ni=0; ni<6; ni++) bv[ni] = bias[wn + ni*16 + l15];

  if (MODE != 2){
    #pragma unroll
    for (int mi=0; mi<4; mi++){
      #pragma unroll
      for (int r=0; r<4; r++){
        long gp = (long)(m0 + wm + mi*16 + q*4 + r)*CCH + wn;
        #pragma unroll
        for (int ni=0; ni<6; ni++){
          float v = acc[mi][ni][r] + bv[ni];
          if (MODE == 0) v = gelu_exact(v);
          out16[gp + ni*16 + l15] = f2b(v);
        }
      }
    }
  } else {
    const int slot = wv >> 1;
    #pragma unroll
    for (int mi=0; mi<4; mi++){
      #pragma unroll
      for (int r=0; r<4; r++){
        int pixl = wm + mi*16 + q*4 + r;
        long gp = (long)(m0 + pixl)*CCH + wn;
        float s = 0.f, s2 = 0.f;
        #pragma unroll
        for (int ni=0; ni<6; ni++){
          float v = acc[mi][ni][r] + bv[ni] + xres[gp + ni*16 + l15];
          acc[mi][ni][r] = v;
          s += v; s2 = fmaf(v, v, s2);
        }
        s  += __shfl_xor(s, 1);  s  += __shfl_xor(s, 2);
        s  += __shfl_xor(s, 4);  s  += __shfl_xor(s, 8);
        s2 += __shfl_xor(s2, 1); s2 += __shfl_xor(s2, 2);
        s2 += __shfl_xor(s2, 4); s2 += __shfl_xor(s2, 8);
        if (l15 == 0){ reds[pixl*2 + slot] = s; reds2[pixl*2 + slot] = s2; }
      }
    }
    __syncthreads();
    #pragma unroll
    for (int mi=0; mi<4; mi++){
      #pragma unroll
      for (int r=0; r<4; r++){
        int pixl = wm + mi*16 + q*4 + r;
        long gp = (long)(m0 + pixl)*CCH + wn;
        float st  = reds[pixl*2] + reds[pixl*2+1];
        float s2t = reds2[pixl*2] + reds2[pixl*2+1];
        float mu = st * (1.0f/192.0f);
        float var = s2t * (1.0f/192.0f) - mu*mu;
        float rs = rsqrtf(var + 1e-5f);
        #pragma unroll
        for (int ni=0; ni<6; ni++){
          int co = wn + ni*16 + l15;
          float z = (acc[mi][ni][r] - mu) * rs * gam[co] + bet[co];
          out16[gp + ni*16 + l15] = f2b(z);
        }
      }
    }
  }
}

// ------- depthwise 5x5 conv on NHWC bf16, 8 channels/thread, XCD-swizzled ---
template<int PAD, int DIL>
__global__ __launch_bounds__(256) void dw_nhwc(
    const unsigned short* __restrict__ in16, const float* __restrict__ wT, // [25][192]
    const float* __restrict__ bias, unsigned short* __restrict__ out16)
{
  const int g = blockIdx.x;                   // grid = 6144
  const int wid = (g & 7) * 768 + (g >> 3);   // XCD swizzle: contiguous spans
  const int t = wid*256 + threadIdx.x;
  const int c8 = t % 24, pix = t / 24;
  const int row = (pix >> 7) & 127, col = pix & 127;
  const int c0 = c8 * 8;
  const long ibase = (long)(pix & ~(HWC-1)) * CCH;   // image-plane base (b*16384*192)
  float acc[8];
  {
    float4 b0 = *(const float4*)&bias[c0], b1 = *(const float4*)&bias[c0+4];
    acc[0]=b0.x; acc[1]=b0.y; acc[2]=b0.z; acc[3]=b0.w;
    acc[4]=b1.x; acc[5]=b1.y; acc[6]=b1.z; acc[7]=b1.w;
  }
  #pragma unroll
  for (int kh=0; kh<5; kh++){
    int ih = row + kh*DIL - PAD;
    if ((unsigned)ih < 128u){
      #pragma unroll
      for (int kw=0; kw<5; kw++){
        int iw = col + kw*DIL - PAD;
        if ((unsigned)iw < 128u){
          uint4 v = *(const uint4*)(in16 + ibase + (long)(ih*128 + iw)*CCH + c0);
          const float* wp = wT + (kh*5 + kw)*CCH + c0;
          float4 w0 = *(const float4*)wp, w1 = *(const float4*)(wp + 4);
          unsigned int uu[4] = {v.x, v.y, v.z, v.w};
          float wa[8] = {w0.x, w0.y, w0.z, w0.w, w1.x, w1.y, w1.z, w1.w};
          #pragma unroll
          for (int j=0; j<8; j++){
            float xv = b2f(uu[j>>1] >> ((j&1)*16));
            acc[j] = fmaf(wa[j], xv, acc[j]);
          }
        }
      }
    }
  }
  unsigned int rr[4];
  #pragma unroll
  for (int wq2=0; wq2<4; wq2++)
    rr[wq2] = (unsigned int)f2b(acc[wq2*2]) | ((unsigned int)f2b(acc[wq2*2+1]) << 16);
  uint4 o; o.x=rr[0]; o.y=rr[1]; o.z=rr[2]; o.w=rr[3];
  *(uint4*)(out16 + (long)pix*CCH + c0) = o;
}

// ---------------- qkv GEMM via MFMA: z16[65536][192] @ WQ^T -> qkv f32 ------
__global__ __launch_bounds__(256, 3) void qkv_mfma(
    const unsigned short* __restrict__ z16,   // [65536][192] bf16
    const unsigned short* __restrict__ w16,   // [576][192] bf16
    const float* __restrict__ qb, const float* __restrict__ vb,
    float* __restrict__ qkv)                  // [65536][576] f32
{
  __shared__ unsigned short sA[128*LDA];      // 51200 B
  const int tid = threadIdx.x;
  const int m0 = blockIdx.x * 128;            // pixel base
  const int s  = blockIdx.y;                  // 0=q,1=k,2=v
  #pragma unroll
  for (int i=0;i<12;i++){
    int idx = tid + i*256;
    int row = idx / 24, oct = idx - row*24;
    uint4 v = *(const uint4*)(z16 + (long)(m0+row)*CCH + oct*8);
    *(uint4*)&sA[row*LDA + oct*8] = v;
  }
  __syncthreads();
  const int wv = tid >> 6, lane = tid & 63;
  const int wm = (wv & 1) * 64;               // pix offset in tile
  const int wn = (wv >> 1) * 96;              // co offset in slice
  const int l15 = lane & 15, q = lane >> 4;
  const unsigned short* wbase = w16 + (long)(s*192)*CCH;
  f32x4 acc[4][6];
  #pragma unroll
  for (int mi=0;mi<4;mi++)
    #pragma unroll
    for (int ni=0;ni<6;ni++) acc[mi][ni] = (f32x4){0.f,0.f,0.f,0.f};
  #pragma unroll
  for (int kk=0; kk<6; kk++){
    const int k0 = kk*32;
    short8x af[4], bf[6];
    #pragma unroll
    for (int mi=0; mi<4; mi++)
      af[mi] = *(const short8x*)&sA[(wm + mi*16 + l15)*LDA + k0 + q*8];
    #pragma unroll
    for (int ni=0; ni<6; ni++)
      bf[ni] = *(const short8x*)(wbase + (long)(wn + ni*16 + l15)*CCH + k0 + q*8);
    #pragma unroll
    for (int mi=0; mi<4; mi++)
      #pragma unroll
      for (int ni=0; ni<6; ni++)
        acc[mi][ni] = __builtin_amdgcn_mfma_f32_16x16x32_bf16(af[mi], bf[ni], acc[mi][ni], 0,0,0);
  }
  #pragma unroll
  for (int ni=0; ni<6; ni++){
    int co = wn + ni*16 + l15;                // 0..191 within slice
    float bv = (s==0) ? qb[co] : ((s==2) ? vb[co] : 0.0f);
    #pragma unroll
    for (int mi=0; mi<4; mi++){
      #pragma unroll
      for (int r=0; r<4; r++){
        int pix = m0 + wm + mi*16 + q*4 + r;
        qkv[(long)pix*576 + s*192 + co] = acc[mi][ni][r] + bv;
      }
    }
  }
}

// ---------------- CPB MLP: table(961,2) -> (961,6) --------------------------
__device__ __forceinline__ float cpb_coord(int a){
  float r = ((float)a - 15.0f) * (8.0f/15.0f);
  float t = log2f(fabsf(r) + 1.0f) * (1.0f/3.0f);
  return (r < 0.f) ? -t : t;
}
__global__ __launch_bounds__(128) void cpb_mlp_kernel(
    const float* __restrict__ w1, const float* __restrict__ b1,
    const float* __restrict__ w2, float* __restrict__ tbl6)
{
  int e = blockIdx.x;
  int a = e / 31, bb = e - a*31;
  float t0 = cpb_coord(a), t1 = cpb_coord(bb);
  float p[6] = {0,0,0,0,0,0};
  for (int hh = threadIdx.x; hh < 512; hh += 128){
    float hid = t0*w1[hh*2] + t1*w1[hh*2+1] + b1[hh];
    hid = fmaxf(hid, 0.0f);
    #pragma unroll
    for (int hd=0; hd<6; hd++) p[hd] = fmaf(hid, w2[hd*512 + hh], p[hd]);
  }
  __shared__ float red[6][128];
  #pragma unroll
  for (int hd=0; hd<6; hd++) red[hd][threadIdx.x] = p[hd];
  __syncthreads();
  if (threadIdx.x < 6){
    float sum = 0.f;
    for (int i=0;i<128;i++) sum += red[threadIdx.x][i];
    tbl6[e*6 + threadIdx.x] = sum;
  }
}
// expand to bias[h][i][j] = 16*sigmoid(tbl6[relidx(i,j)][h]) - 16  (shift folded
// in so attention exponents are <= 10: softmax is shift-invariant)
__global__ __launch_bounds__(256) void cpb_expand_kernel(
    const float* __restrict__ tbl6, float* __restrict__ bias)
{
  int idx = blockIdx.x*256 + threadIdx.x;      // < 6*256*256
  int h = idx >> 16;
  int rem = idx & 65535;
  int i = rem >> 8, j = rem & 255;
  int dy = (i>>4) - (j>>4) + 15;
  int dx = (i&15) - (j&15) + 15;
  float v = tbl6[(dy*31+dx)*6 + h];
  bias[idx] = 16.0f / (1.0f + __expf(-v)) - 16.0f;
}

// ------------- windowed cosine attention via MFMA, block=(win, head) --------
#define KSP 40    // ks/qs/ps row stride (shorts): 80 B, 16B-aligned, 2-way banks
#define VTP 264   // vt row stride (shorts): 528 B, 16B-aligned, 2-way banks
__global__ __launch_bounds__(256) void attn_mfma(
    const float* __restrict__ qkv, const float* __restrict__ bias,
    const float* __restrict__ ls, unsigned short* __restrict__ aout)
{
  __shared__ unsigned short ks[256*KSP];      // 20480 B  kn bf16 [key][d]
  __shared__ unsigned short vt[32*VTP];       // 16896 B  v bf16 [d][key]
  __shared__ unsigned short ps[4][64*KSP];    // 20480 B  per-wave P / (init: qs)
  unsigned short* qs = &ps[0][0];             // 256*40 shorts fits 4*2560

  const int win = blockIdx.x, h = blockIdx.y;
  const int t = threadIdx.x;
  const int bb = win >> 6;
  const int wy = (win >> 3) & 7, wx = win & 7;
  const float sc = __expf(fminf(ls[h], 4.60517018598809136804f));  // ln(100)

  { // ---- stage qn, kn (token t) ----
    const int ty = t >> 4, tx = t & 15;
    const int pix = bb*HWC + (wy*16+ty)*128 + wx*16 + tx;
    const float* row = qkv + (long)pix*576 + h*32;
    float qv[32], kv[32];
    float sq = 0.f, sk = 0.f;
    #pragma unroll
    for (int d=0; d<32; d+=4){
      float4 a = *(const float4*)(row + d);
      float4 b = *(const float4*)(row + 192 + d);
      qv[d]=a.x; qv[d+1]=a.y; qv[d+2]=a.z; qv[d+3]=a.w;
      kv[d]=b.x; kv[d+1]=b.y; kv[d+2]=b.z; kv[d+3]=b.w;
      sq += a.x*a.x + a.y*a.y + a.z*a.z + a.w*a.w;
      sk += b.x*b.x + b.y*b.y + b.z*b.z + b.w*b.w;
    }
    float qinv = sc / fmaxf(sqrtf(sq), 1e-12f);
    float kinv = 1.0f / fmaxf(sqrtf(sk), 1e-12f);
    union { unsigned short u[32]; uint4 v4[4]; } qp, kp;
    #pragma unroll
    for (int d=0; d<32; d++){ qp.u[d] = f2b(qv[d]*qinv); kp.u[d] = f2b(kv[d]*kinv); }
    #pragma unroll
    for (int o=0;o<4;o++){
      *(uint4*)&qs[t*KSP + o*8] = qp.v4[o];
      *(uint4*)&ks[t*KSP + o*8] = kp.v4[o];
    }
  }
  { // ---- stage v transposed: thread (d, kt) handles 32 keys for dim d ----
    const int d = t & 31, kt = t >> 5;
    union { unsigned short u[32]; uint4 v4[4]; } vp;
    #pragma unroll 4
    for (int i=0;i<32;i++){
      int key = kt*32 + i;
      int pixk = bb*HWC + (wy*16 + (key>>4))*128 + wx*16 + (key&15);
      vp.u[i] = f2b(qkv[(long)pixk*576 + 384 + h*32 + d]);
    }
    #pragma unroll
    for (int o=0;o<4;o++) *(uint4*)&vt[d*VTP + kt*32 + o*8] = vp.v4[o];
  }
  __syncthreads();

  const int wv = t >> 6, lane = t & 63;
  const int l15 = lane & 15, q = lane >> 4;
  short8x qa[4];
  #pragma unroll
  for (int mi=0; mi<4; mi++)
    qa[mi] = *(const short8x*)&qs[(wv*64 + mi*16 + l15)*KSP + q*8];
  __syncthreads();   // qs region now free for ps use

  f32x4 oacc[4][2], lsum[4];
  #pragma unroll
  for (int mi=0;mi<4;mi++){
    oacc[mi][0] = (f32x4){0.f,0.f,0.f,0.f};
    oacc[mi][1] = (f32x4){0.f,0.f,0.f,0.f};
    lsum[mi]    = (f32x4){0.f,0.f,0.f,0.f};
  }
  const float* bias_h = bias + (h << 16);
  unsigned short* myps = ps[wv];

  for (int kt=0; kt<8; kt++){
    const int k0 = kt*32;
    short8x kb0 = *(const short8x*)&ks[(k0 + l15)*KSP + q*8];
    short8x kb1 = *(const short8x*)&ks[(k0 + 16 + l15)*KSP + q*8];
    f32x4 s[4][2];
    #pragma unroll
    for (int mi=0; mi<4; mi++){
      f32x4 z0 = (f32x4){0.f,0.f,0.f,0.f};
      s[mi][0] = __builtin_amdgcn_mfma_f32_16x16x32_bf16(qa[mi], kb0, z0, 0,0,0);
      s[mi][1] = __builtin_amdgcn_mfma_f32_16x16x32_bf16(qa[mi], kb1, z0, 0,0,0);
    }
    #pragma unroll
    for (int mi=0; mi<4; mi++){
      #pragma unroll
      for (int r=0; r<4; r++){
        int rowq = wv*64 + mi*16 + q*4 + r;
        const float* brow = bias_h + rowq*256 + k0;
        float e0 = __expf(fminf(s[mi][0][r] + brow[l15],      30.f));
        float e1 = __expf(fminf(s[mi][1][r] + brow[16 + l15], 30.f));
        lsum[mi][r] += e0 + e1;
        myps[(mi*16 + q*4 + r)*KSP + l15]      = f2b(e0);
        myps[(mi*16 + q*4 + r)*KSP + 16 + l15] = f2b(e1);
      }
    }
    short8x vb0 = *(const short8x*)&vt[(l15)*VTP      + k0 + q*8];
    short8x vb1 = *(const short8x*)&vt[(16 + l15)*VTP + k0 + q*8];
    #pragma unroll
    for (int mi=0; mi<4; mi++){
      short8x pa = *(const short8x*)&myps[(mi*16 + l15)*KSP + q*8];
      oacc[mi][0] = __builtin_amdgcn_mfma_f32_16x16x32_bf16(pa, vb0, oacc[mi][0], 0,0,0);
      oacc[mi][1] = __builtin_amdgcn_mfma_f32_16x16x32_bf16(pa, vb1, oacc[mi][1], 0,0,0);
    }
  }
  #pragma unroll
  for (int mi=0; mi<4; mi++){
    #pragma unroll
    for (int r=0; r<4; r++){
      float v = lsum[mi][r];
      v += __shfl_xor(v, 1);
      v += __shfl_xor(v, 2);
      v += __shfl_xor(v, 4);
      v += __shfl_xor(v, 8);
      lsum[mi][r] = v;
    }
  }
  #pragma unroll
  for (int mi=0; mi<4; mi++){
    #pragma unroll
    for (int r=0; r<4; r++){
      int rowq = wv*64 + mi*16 + q*4 + r;
      int pixo = bb*HWC + (wy*16 + (rowq>>4))*128 + wx*16 + (rowq&15);
      float inv = 1.0f / lsum[mi][r];
      aout[(long)pixo*CCH + h*32 + l15]      = f2b(oacc[mi][0][r]*inv);
      aout[(long)pixo*CCH + h*32 + 16 + l15] = f2b(oacc[mi][1][r]*inv);
    }
  }
}

// ------- proj GEMM via MFMA: aout16 @ WP^T + b -> NCHW f32 (coalesced) ------
__global__ __launch_bounds__(256, 3) void proj_mfma(
    const unsigned short* __restrict__ a16,   // [65536][192] bf16
    const unsigned short* __restrict__ w16,   // [192][192] bf16
    const float* __restrict__ bias,
    float* __restrict__ outp)                 // NCHW f32
{
  __shared__ unsigned short sB[128*LDA];
  const int tid = threadIdx.x;
  const int n0 = blockIdx.x * 128;            // pixel base
  #pragma unroll
  for (int i=0;i<12;i++){
    int idx = tid + i*256;
    int row = idx / 24, oct = idx - row*24;
    uint4 v = *(const uint4*)(a16 + (long)(n0+row)*CCH + oct*8);
    *(uint4*)&sB[row*LDA + oct*8] = v;
  }
  __syncthreads();
  const int wv = tid >> 6, lane = tid & 63;
  const int wm = (wv & 1) * 96;               // co offset
  const int wn = (wv >> 1) * 64;              // pix offset in tile
  const int l15 = lane & 15, q = lane >> 4;
  f32x4 acc[6][4];
  #pragma unroll
  for (int mi=0;mi<6;mi++)
    #pragma unroll
    for (int ni=0;ni<4;ni++) acc[mi][ni] = (f32x4){0.f,0.f,0.f,0.f};
  #pragma unroll
  for (int kk=0; kk<6; kk++){
    const int k0 = kk*32;
    short8x af[6], bf[4];
    #pragma unroll
    for (int mi=0; mi<6; mi++)
      af[mi] = *(const short8x*)(w16 + (long)(wm + mi*16 + l15)*CCH + k0 + q*8);
    #pragma unroll
    for (int ni=0; ni<4; ni++)
      bf[ni] = *(const short8x*)&sB[(wn + ni*16 + l15)*LDA + k0 + q*8];
    #pragma unroll
    for (int mi=0; mi<6; mi++)
      #pragma unroll
      for (int ni=0; ni<4; ni++)
        acc[mi][ni] = __builtin_amdgcn_mfma_f32_16x16x32_bf16(af[mi], bf[ni], acc[mi][ni], 0,0,0);
  }
  #pragma unroll
  for (int mi=0; mi<6; mi++){
    #pragma unroll
    for (int r=0; r<4; r++){
      int co = wm + mi*16 + q*4 + r;
      float bv = bias[co];
      #pragma unroll
      for (int ni=0; ni<4; ni++){
        int pix = n0 + wn + ni*16 + l15;
        int b = pix >> 14, hw = pix & (HWC-1);
        outp[((long)b*CCH + co)*HWC + hw] = acc[mi][ni][r] + bv;
      }
    }
  }
}

// ---------------------------------------------------------------------------
extern "C" void kernel_launch(void* const* d_in, const int* in_sizes, int n_in,
                              void* d_out, int out_size, void* d_ws, size_t ws_size,
                              hipStream_t stream)
{
  const float* x       = (const float*)d_in[0];
  const float* p1_w    = (const float*)d_in[1];
  const float* p1_b    = (const float*)d_in[2];
  const float* pw_w    = (const float*)d_in[3];
  const float* pw_b    = (const float*)d_in[4];
  const float* dw_w    = (const float*)d_in[5];
  const float* dw_b    = (const float*)d_in[6];
  const float* dd_w    = (const float*)d_in[7];
  const float* dd_b    = (const float*)d_in[8];
  const float* p2_w    = (const float*)d_in[9];
  const float* p2_b    = (const float*)d_in[10];
  const float* ln_g    = (const float*)d_in[11];
  const float* ln_b    = (const float*)d_in[12];
  const float* qkv_w   = (const float*)d_in[13];
  const float* q_bias  = (const float*)d_in[14];
  const float* v_bias  = (const float*)d_in[15];
  const float* lscale  = (const float*)d_in[16];
  const float* cpb_w1  = (const float*)d_in[17];
  const float* cpb_b1  = (const float*)d_in[18];
  const float* cpb_w2  = (const float*)d_in[19];
  const float* proj_w  = (const float*)d_in[20];
  const float* proj_b  = (const float*)d_in[21];

  float* ws = (float*)d_ws;
  const long A = 12582912L;           // 4*192*128*128
  // conv phase: [0,2A) = bf16 buffers, [2A,3A) = xT32; qkv f32 later spans [0,3A)
  unsigned short* X16  = (unsigned short*)ws;                 // [0, A/2)
  unsigned short* Y16  = (unsigned short*)(ws + A/2);         // [A/2, A)
  unsigned short* A16  = (unsigned short*)(ws + A);           // [A, 1.5A)
  unsigned short* T16  = (unsigned short*)(ws + A + A/2);     // [1.5A, 2A)
  float* XT32 = ws + 2*A;                                     // [2A, 3A)
  float* R0   = ws;                                           // qkv f32 out
  unsigned short* Z16  = (unsigned short*)(ws + 3*A);         // [3A, 3.5A)
  unsigned short* AO16 = Z16;                                 // attn out reuses z16
  float* DWT = ws + 3*A + A/2;                                // 4800
  float* DDT = DWT + 4800;                                    // 4800
  unsigned short* WQ   = (unsigned short*)(DDT + 4800);       // 110592
  unsigned short* WPRJ = WQ + 110592;                         // 36864
  unsigned short* WP1  = WPRJ + 36864;
  unsigned short* WPA  = WP1 + 36864;
  unsigned short* WP2  = WPA + 36864;
  float* RB = ws + 4*A;               // bias table (6*256*256), shifted by -16
  float* T6 = RB + 393216;            // cpb mlp out (961*6)

  // weight prep + CPB bias table (independent of main chain)
  cast_w_kernel<<<432, 256, 0, stream>>>(qkv_w, proj_w, p1_w, pw_w, p2_w, dw_w, dd_w,
                                         WQ, WPRJ, WP1, WPA, WP2, DWT, DDT);
  cpb_mlp_kernel<<<961, 128, 0, stream>>>(cpb_w1, cpb_b1, cpb_w2, T6);
  cpb_expand_kernel<<<1536, 256, 0, stream>>>(T6, RB);

  // x -> NHWC (f32 residual + bf16)
  tx_kernel<<<1024, 256, 0, stream>>>(x, XT32, X16);

  // VAB conv block, all MFMA / NHWC bf16
  pw_mfma<0><<<512, 256, 0, stream>>>(X16, nullptr, WP1, p1_b, nullptr, nullptr, nullptr, Y16);
  pw_mfma<1><<<512, 256, 0, stream>>>(Y16, nullptr, WPA, pw_b, nullptr, nullptr, nullptr, A16);
  dw_nhwc<2,1><<<6144, 256, 0, stream>>>(A16, DWT, dw_b, T16);
  dw_nhwc<6,3><<<6144, 256, 0, stream>>>(T16, DDT, dd_b, A16);
  // proj_2 + residual + fused LayerNorm -> z16
  pw_mfma<2><<<512, 256, 0, stream>>>(Y16, A16, WP2, p2_b, XT32, ln_g, ln_b, Z16);

  // qkv GEMM on MFMA (bf16 buffers dead -> qkv f32 occupies [0,3A))
  qkv_mfma<<<dim3(512, 3), 256, 0, stream>>>(Z16, WQ, q_bias, v_bias, R0);

  // window attention on MFMA
  attn_mfma<<<dim3(256, 6), 256, 0, stream>>>(R0, RB, lscale, AO16);

  // projection on MFMA + window-reverse -> f32 NCHW
  proj_mfma<<<512, 256, 0, stream>>>(AO16, WPRJ, proj_b, (float*)d_out);
}